// Round 1
// baseline (822.680 us; speedup 1.0000x reference)
//
#include <hip/hip_runtime.h>
#include <hip/hip_bf16.h>
#include <cstdint>
#include <cstddef>

#define N_NODES 100000
#define N_EDGES 1600000
#define EPSV 1e-5f

// ---- workspace layout (bytes) ----
// rowptr: (N+1) ints        @ 0
// deg/cursor: N ints        @ 400384
// bn: 256 floats            @ 800768   (sum|sumsq -> scale|shift)
// ssrc: E ints              @ 801792   (src ids sorted by dst)
// t1r1: N*256 f32           @ 7201792  (x@Wl1 | x@Wr1), later reused as t2r2 (N*128 f32)
// hpre: N*128 f32           @ 109601792
// total bytes needed: 160801792
#define OFF_ROWPTR 0
#define OFF_DEG    400384
#define OFF_BN     800768
#define OFF_SRC    801792
#define OFF_T1R1   7201792
#define OFF_HPRE   109601792

// ---------- CSR build ----------
__global__ __launch_bounds__(256) void k_hist(const int* __restrict__ dst, int* __restrict__ deg) {
    int e = blockIdx.x * 256 + threadIdx.x;   // grid covers E exactly
    atomicAdd(&deg[dst[e]], 1);
}

__global__ __launch_bounds__(1024) void k_scan(int* __restrict__ degcur, int* __restrict__ rowptr) {
    __shared__ int sums[1024];
    const int t = threadIdx.x;
    const int C = (N_NODES + 1023) >> 10;  // 98
    int lo = t * C, hi = lo + C;
    if (lo > N_NODES) lo = N_NODES;
    if (hi > N_NODES) hi = N_NODES;
    int s = 0;
    for (int i = lo; i < hi; ++i) s += degcur[i];
    sums[t] = s;
    __syncthreads();
    for (int off = 1; off < 1024; off <<= 1) {
        int v = (t >= off) ? sums[t - off] : 0;
        __syncthreads();
        sums[t] += v;
        __syncthreads();
    }
    int run = (t == 0) ? 0 : sums[t - 1];
    for (int i = lo; i < hi; ++i) {
        int d = degcur[i];
        rowptr[i] = run;
        degcur[i] = run;   // becomes scatter cursor
        run += d;
    }
    if (t == 1023) rowptr[N_NODES] = sums[1023];
}

__global__ __launch_bounds__(256) void k_scatter(const int* __restrict__ src, const int* __restrict__ dst,
                                                 int* __restrict__ cursor, int* __restrict__ ssrc) {
    int e = blockIdx.x * 256 + threadIdx.x;
    int d = dst[e];
    int pos = atomicAdd(&cursor[d], 1);
    ssrc[pos] = src[e];
}

// ---------- layer 1 GEMM: t1|r1 = x @ [Wl1 | Wr1]  (N x 128 @ 128 x 256) ----------
__global__ __launch_bounds__(128) void k_gemm1(const float* __restrict__ x, const float* __restrict__ Wl,
                                               const float* __restrict__ Wr, float* __restrict__ t1r1) {
    __shared__ float xs[16 * 128];
    const int tid = threadIdx.x;
    const size_t n0 = (size_t)blockIdx.x * 16;     // 6250*16 = 100000 exact
    const float* xb = x + n0 * 128;
#pragma unroll
    for (int i = 0; i < 16; ++i) xs[tid + i * 128] = xb[tid + i * 128];
    __syncthreads();

    const float* wl = Wl + tid;   // column tid of Wl1 [128][128]
    const float* wr = Wr + tid;   // column tid of Wr1
    float accL[16], accR[16];
#pragma unroll
    for (int n = 0; n < 16; ++n) { accL[n] = 0.f; accR[n] = 0.f; }

    for (int k = 0; k < 128; k += 4) {
        float wl0 = wl[(k + 0) * 128], wl1 = wl[(k + 1) * 128], wl2 = wl[(k + 2) * 128], wl3 = wl[(k + 3) * 128];
        float wr0 = wr[(k + 0) * 128], wr1 = wr[(k + 1) * 128], wr2 = wr[(k + 2) * 128], wr3 = wr[(k + 3) * 128];
#pragma unroll
        for (int n = 0; n < 16; ++n) {
            float4 xv = *(const float4*)&xs[n * 128 + k];
            accL[n] = fmaf(xv.x, wl0, accL[n]);
            accL[n] = fmaf(xv.y, wl1, accL[n]);
            accL[n] = fmaf(xv.z, wl2, accL[n]);
            accL[n] = fmaf(xv.w, wl3, accL[n]);
            accR[n] = fmaf(xv.x, wr0, accR[n]);
            accR[n] = fmaf(xv.y, wr1, accR[n]);
            accR[n] = fmaf(xv.z, wr2, accR[n]);
            accR[n] = fmaf(xv.w, wr3, accR[n]);
        }
    }
    float* ob = t1r1 + n0 * 256;
#pragma unroll
    for (int n = 0; n < 16; ++n) {
        ob[n * 256 + tid] = accL[n];
        ob[n * 256 + 128 + tid] = accR[n];
    }
}

// ---------- layer 1 aggregate + bias + BN partials ----------
__global__ __launch_bounds__(128) void k_agg1(const float* __restrict__ t1r1, const int* __restrict__ rowptr,
                                              const int* __restrict__ ssrc, const float* __restrict__ b1,
                                              float* __restrict__ hpre, float* __restrict__ bn) {
    const int tid = threadIdx.x;
    const int nbase = blockIdx.x * 32;             // 3125*32 = 100000 exact
    const float bias = b1[tid];
    float bsum = 0.f, bsq = 0.f;
    for (int ni = 0; ni < 32; ++ni) {
        const int n = nbase + ni;
        const int lo = rowptr[n], hi = rowptr[n + 1];
        float a0 = 0.f, a1 = 0.f, a2 = 0.f, a3 = 0.f;
        int i = lo;
        for (; i + 4 <= hi; i += 4) {
            int s0 = ssrc[i], s1 = ssrc[i + 1], s2 = ssrc[i + 2], s3 = ssrc[i + 3];
            a0 += t1r1[(size_t)s0 * 256 + tid];
            a1 += t1r1[(size_t)s1 * 256 + tid];
            a2 += t1r1[(size_t)s2 * 256 + tid];
            a3 += t1r1[(size_t)s3 * 256 + tid];
        }
        for (; i < hi; ++i) a0 += t1r1[(size_t)ssrc[i] * 256 + tid];
        float acc = (a0 + a1) + (a2 + a3);
        float c = (float)(hi - lo);
        if (c < 1.f) c = 1.f;
        float v = acc / c + bias + t1r1[(size_t)n * 256 + 128 + tid];
        hpre[(size_t)n * 128 + tid] = v;
        bsum += v;
        bsq += v * v;
    }
    atomicAdd(&bn[tid], bsum);
    atomicAdd(&bn[128 + tid], bsq);
}

// ---------- BN finalize: sum|sumsq -> scale|shift ----------
__global__ void k_bnfin(float* __restrict__ bn, const float* __restrict__ gamma, const float* __restrict__ beta) {
    int f = threadIdx.x;  // 128 threads
    float mean = bn[f] * (1.0f / N_NODES);
    float var = bn[128 + f] * (1.0f / N_NODES) - mean * mean;
    float sc = gamma[f] * rsqrtf(var + EPSV);
    bn[f] = sc;
    bn[128 + f] = beta[f] - mean * sc;
}

// ---------- layer 2 GEMM with fused BN+ReLU: t2|r2 = relu(bn(hpre)) @ [Wl2 | Wr2] ----------
__global__ __launch_bounds__(64) void k_gemm2(const float* __restrict__ hpre, const float* __restrict__ bn,
                                              const float* __restrict__ Wl, const float* __restrict__ Wr,
                                              float* __restrict__ t2r2) {
    __shared__ float hs[16 * 128];
    const int tid = threadIdx.x;  // 0..63
    const size_t n0 = (size_t)blockIdx.x * 16;     // 6250*16 = 100000 exact
    const float sc0 = bn[tid], sc1 = bn[tid + 64];
    const float sh0 = bn[128 + tid], sh1 = bn[192 + tid];
    const float* hb = hpre + n0 * 128;
#pragma unroll
    for (int i = 0; i < 32; ++i) {
        int idx = tid + i * 64;        // column = tid (i even) or tid+64 (i odd)
        float v = hb[idx];
        float sc = (i & 1) ? sc1 : sc0;
        float sh = (i & 1) ? sh1 : sh0;
        v = fmaf(sc, v, sh);
        hs[idx] = v > 0.f ? v : 0.f;
    }
    __syncthreads();

    const float* wl = Wl + tid;   // column tid of Wl2 [128][64]
    const float* wr = Wr + tid;
    float accL[16], accR[16];
#pragma unroll
    for (int n = 0; n < 16; ++n) { accL[n] = 0.f; accR[n] = 0.f; }

    for (int k = 0; k < 128; k += 4) {
        float wl0 = wl[(k + 0) * 64], wl1 = wl[(k + 1) * 64], wl2 = wl[(k + 2) * 64], wl3 = wl[(k + 3) * 64];
        float wr0 = wr[(k + 0) * 64], wr1 = wr[(k + 1) * 64], wr2 = wr[(k + 2) * 64], wr3 = wr[(k + 3) * 64];
#pragma unroll
        for (int n = 0; n < 16; ++n) {
            float4 hv = *(const float4*)&hs[n * 128 + k];
            accL[n] = fmaf(hv.x, wl0, accL[n]);
            accL[n] = fmaf(hv.y, wl1, accL[n]);
            accL[n] = fmaf(hv.z, wl2, accL[n]);
            accL[n] = fmaf(hv.w, wl3, accL[n]);
            accR[n] = fmaf(hv.x, wr0, accR[n]);
            accR[n] = fmaf(hv.y, wr1, accR[n]);
            accR[n] = fmaf(hv.z, wr2, accR[n]);
            accR[n] = fmaf(hv.w, wr3, accR[n]);
        }
    }
    float* ob = t2r2 + n0 * 128;
#pragma unroll
    for (int n = 0; n < 16; ++n) {
        ob[n * 128 + tid] = accL[n];
        ob[n * 128 + 64 + tid] = accR[n];
    }
}

// ---------- layer 2 aggregate + bias -> out ----------
__global__ __launch_bounds__(64) void k_agg2(const float* __restrict__ t2r2, const int* __restrict__ rowptr,
                                             const int* __restrict__ ssrc, const float* __restrict__ b2,
                                             float* __restrict__ out) {
    const int tid = threadIdx.x;  // 0..63
    const int nbase = blockIdx.x * 16;             // 6250*16 = 100000 exact
    const float bias = b2[tid];
    for (int ni = 0; ni < 16; ++ni) {
        const int n = nbase + ni;
        const int lo = rowptr[n], hi = rowptr[n + 1];
        float a0 = 0.f, a1 = 0.f, a2 = 0.f, a3 = 0.f;
        int i = lo;
        for (; i + 4 <= hi; i += 4) {
            int s0 = ssrc[i], s1 = ssrc[i + 1], s2 = ssrc[i + 2], s3 = ssrc[i + 3];
            a0 += t2r2[(size_t)s0 * 128 + tid];
            a1 += t2r2[(size_t)s1 * 128 + tid];
            a2 += t2r2[(size_t)s2 * 128 + tid];
            a3 += t2r2[(size_t)s3 * 128 + tid];
        }
        for (; i < hi; ++i) a0 += t2r2[(size_t)ssrc[i] * 128 + tid];
        float acc = (a0 + a1) + (a2 + a3);
        float c = (float)(hi - lo);
        if (c < 1.f) c = 1.f;
        out[(size_t)n * 64 + tid] = acc / c + bias + t2r2[(size_t)n * 128 + 64 + tid];
    }
}

extern "C" void kernel_launch(void* const* d_in, const int* in_sizes, int n_in,
                              void* d_out, int out_size, void* d_ws, size_t ws_size,
                              hipStream_t stream) {
    const float* x      = (const float*)d_in[0];
    const int*   ei     = (const int*)d_in[1];
    const float* Wl1    = (const float*)d_in[2];
    const float* b1     = (const float*)d_in[3];
    const float* Wr1    = (const float*)d_in[4];
    const float* gamma1 = (const float*)d_in[5];
    const float* beta1  = (const float*)d_in[6];
    const float* Wl2    = (const float*)d_in[7];
    const float* b2     = (const float*)d_in[8];
    const float* Wr2    = (const float*)d_in[9];
    float* out = (float*)d_out;

    char* ws = (char*)d_ws;
    int*   rowptr = (int*)(ws + OFF_ROWPTR);
    int*   deg    = (int*)(ws + OFF_DEG);     // also scatter cursor
    float* bn     = (float*)(ws + OFF_BN);
    int*   ssrc   = (int*)(ws + OFF_SRC);
    float* t1r1   = (float*)(ws + OFF_T1R1);
    float* t2r2   = t1r1;                     // reuse: t1r1 dead after k_agg1
    float* hpre   = (float*)(ws + OFF_HPRE);

    const int* esrc = ei;            // edge_index[0]
    const int* edst = ei + N_EDGES;  // edge_index[1]

    hipMemsetAsync(deg, 0, N_NODES * sizeof(int), stream);
    hipMemsetAsync(bn, 0, 256 * sizeof(float), stream);

    k_hist<<<N_EDGES / 256, 256, 0, stream>>>(edst, deg);
    k_scan<<<1, 1024, 0, stream>>>(deg, rowptr);
    k_scatter<<<N_EDGES / 256, 256, 0, stream>>>(esrc, edst, deg, ssrc);

    k_gemm1<<<N_NODES / 16, 128, 0, stream>>>(x, Wl1, Wr1, t1r1);
    k_agg1<<<N_NODES / 32, 128, 0, stream>>>(t1r1, rowptr, ssrc, b1, hpre, bn);
    k_bnfin<<<1, 128, 0, stream>>>(bn, gamma1, beta1);
    k_gemm2<<<N_NODES / 16, 64, 0, stream>>>(hpre, bn, Wl2, Wr2, t2r2);
    k_agg2<<<N_NODES / 16, 64, 0, stream>>>(t2r2, rowptr, ssrc, b2, out);
}

// Round 2
// 600.962 us; speedup vs baseline: 1.3689x; 1.3689x over previous
//
#include <hip/hip_runtime.h>
#include <hip/hip_bf16.h>
#include <cstdint>
#include <cstddef>

#define N_NODES 100000
#define N_EDGES 1600000
#define EPSV 1e-5f

// ---- workspace layout (bytes) ----
#define OFF_ROWPTR 0
#define OFF_DEG    400384
#define OFF_BN     800768
#define OFF_SRC    801792
#define OFF_T1R1   7201792
#define OFF_HPRE   109601792
// bsums (98 ints) overlaps the t1r1 region: scan kernels finish before k_gemm1 writes t1r1.

#define SCAN_NBLK 98   // ceil(100000/1024)

// ---------- CSR build ----------
__global__ __launch_bounds__(256) void k_hist(const int* __restrict__ dst, int* __restrict__ deg) {
    int e = blockIdx.x * 256 + threadIdx.x;   // grid covers E exactly
    atomicAdd(&deg[dst[e]], 1);
}

// phase A: per-block exclusive scan of deg -> rowptr (block-local), block totals -> bsums
__global__ __launch_bounds__(1024) void k_scan_a(const int* __restrict__ deg, int* __restrict__ rowptr,
                                                 int* __restrict__ bsums) {
    __shared__ int s[1024];
    const int t = threadIdx.x;
    const int i = blockIdx.x * 1024 + t;
    int v = (i < N_NODES) ? deg[i] : 0;
    s[t] = v;
    __syncthreads();
    for (int off = 1; off < 1024; off <<= 1) {
        int u = (t >= off) ? s[t - off] : 0;
        __syncthreads();
        s[t] += u;
        __syncthreads();
    }
    if (i < N_NODES) rowptr[i] = s[t] - v;       // exclusive, block-local
    if (t == 1023) bsums[blockIdx.x] = s[1023];  // block total
}

// phase B: exclusive scan of the 98 block sums (single tiny block)
__global__ __launch_bounds__(128) void k_scan_b(int* __restrict__ bsums) {
    __shared__ int s[128];
    const int t = threadIdx.x;
    int v = (t < SCAN_NBLK) ? bsums[t] : 0;
    s[t] = v;
    __syncthreads();
    for (int off = 1; off < 128; off <<= 1) {
        int u = (t >= off) ? s[t - off] : 0;
        __syncthreads();
        s[t] += u;
        __syncthreads();
    }
    if (t < SCAN_NBLK) bsums[t] = s[t] - v;      // exclusive block offsets
}

// phase C: apply block offsets; rowptr final; cursor = rowptr copy
__global__ __launch_bounds__(1024) void k_scan_c(int* __restrict__ rowptr, int* __restrict__ cursor,
                                                 const int* __restrict__ bsums) {
    const int i = blockIdx.x * 1024 + threadIdx.x;
    if (i < N_NODES) {
        int r = rowptr[i] + bsums[blockIdx.x];
        rowptr[i] = r;
        cursor[i] = r;
    }
    if (i == N_NODES) rowptr[N_NODES] = N_EDGES;
}

__global__ __launch_bounds__(256) void k_scatter(const int* __restrict__ src, const int* __restrict__ dst,
                                                 int* __restrict__ cursor, int* __restrict__ ssrc) {
    int e = blockIdx.x * 256 + threadIdx.x;
    int d = dst[e];
    int pos = atomicAdd(&cursor[d], 1);
    ssrc[pos] = src[e];
}

// ---------- layer 1 GEMM: t1|r1 = x @ [Wl1 | Wr1]  (N x 128 @ 128 x 256) ----------
__global__ __launch_bounds__(128) void k_gemm1(const float* __restrict__ x, const float* __restrict__ Wl,
                                               const float* __restrict__ Wr, float* __restrict__ t1r1) {
    __shared__ float xs[16 * 128];
    const int tid = threadIdx.x;
    const size_t n0 = (size_t)blockIdx.x * 16;     // 6250*16 = 100000 exact
    const float* xb = x + n0 * 128;
#pragma unroll
    for (int i = 0; i < 16; ++i) xs[tid + i * 128] = xb[tid + i * 128];
    __syncthreads();

    const float* wl = Wl + tid;   // column tid of Wl1 [128][128]
    const float* wr = Wr + tid;   // column tid of Wr1
    float accL[16], accR[16];
#pragma unroll
    for (int n = 0; n < 16; ++n) { accL[n] = 0.f; accR[n] = 0.f; }

    for (int k = 0; k < 128; k += 4) {
        float wl0 = wl[(k + 0) * 128], wl1 = wl[(k + 1) * 128], wl2 = wl[(k + 2) * 128], wl3 = wl[(k + 3) * 128];
        float wr0 = wr[(k + 0) * 128], wr1 = wr[(k + 1) * 128], wr2 = wr[(k + 2) * 128], wr3 = wr[(k + 3) * 128];
#pragma unroll
        for (int n = 0; n < 16; ++n) {
            float4 xv = *(const float4*)&xs[n * 128 + k];
            accL[n] = fmaf(xv.x, wl0, accL[n]);
            accL[n] = fmaf(xv.y, wl1, accL[n]);
            accL[n] = fmaf(xv.z, wl2, accL[n]);
            accL[n] = fmaf(xv.w, wl3, accL[n]);
            accR[n] = fmaf(xv.x, wr0, accR[n]);
            accR[n] = fmaf(xv.y, wr1, accR[n]);
            accR[n] = fmaf(xv.z, wr2, accR[n]);
            accR[n] = fmaf(xv.w, wr3, accR[n]);
        }
    }
    float* ob = t1r1 + n0 * 256;
#pragma unroll
    for (int n = 0; n < 16; ++n) {
        ob[n * 256 + tid] = accL[n];
        ob[n * 256 + 128 + tid] = accR[n];
    }
}

// ---------- layer 1 aggregate + bias + BN partials ----------
__global__ __launch_bounds__(128) void k_agg1(const float* __restrict__ t1r1, const int* __restrict__ rowptr,
                                              const int* __restrict__ ssrc, const float* __restrict__ b1,
                                              float* __restrict__ hpre, float* __restrict__ bn) {
    const int tid = threadIdx.x;
    const int nbase = blockIdx.x * 32;             // 3125*32 = 100000 exact
    const float bias = b1[tid];
    float bsum = 0.f, bsq = 0.f;
    for (int ni = 0; ni < 32; ++ni) {
        const int n = nbase + ni;
        const int lo = rowptr[n], hi = rowptr[n + 1];
        float a0 = 0.f, a1 = 0.f, a2 = 0.f, a3 = 0.f;
        int i = lo;
        for (; i + 4 <= hi; i += 4) {
            int s0 = ssrc[i], s1 = ssrc[i + 1], s2 = ssrc[i + 2], s3 = ssrc[i + 3];
            a0 += t1r1[(size_t)s0 * 256 + tid];
            a1 += t1r1[(size_t)s1 * 256 + tid];
            a2 += t1r1[(size_t)s2 * 256 + tid];
            a3 += t1r1[(size_t)s3 * 256 + tid];
        }
        for (; i < hi; ++i) a0 += t1r1[(size_t)ssrc[i] * 256 + tid];
        float acc = (a0 + a1) + (a2 + a3);
        float c = (float)(hi - lo);
        if (c < 1.f) c = 1.f;
        float v = acc / c + bias + t1r1[(size_t)n * 256 + 128 + tid];
        hpre[(size_t)n * 128 + tid] = v;
        bsum += v;
        bsq += v * v;
    }
    atomicAdd(&bn[tid], bsum);
    atomicAdd(&bn[128 + tid], bsq);
}

// ---------- BN finalize: sum|sumsq -> scale|shift ----------
__global__ void k_bnfin(float* __restrict__ bn, const float* __restrict__ gamma, const float* __restrict__ beta) {
    int f = threadIdx.x;  // 128 threads
    float mean = bn[f] * (1.0f / N_NODES);
    float var = bn[128 + f] * (1.0f / N_NODES) - mean * mean;
    float sc = gamma[f] * rsqrtf(var + EPSV);
    bn[f] = sc;
    bn[128 + f] = beta[f] - mean * sc;
}

// ---------- layer 2 GEMM with fused BN+ReLU: t2|r2 = relu(bn(hpre)) @ [Wl2 | Wr2] ----------
__global__ __launch_bounds__(64) void k_gemm2(const float* __restrict__ hpre, const float* __restrict__ bn,
                                              const float* __restrict__ Wl, const float* __restrict__ Wr,
                                              float* __restrict__ t2r2) {
    __shared__ float hs[16 * 128];
    const int tid = threadIdx.x;  // 0..63
    const size_t n0 = (size_t)blockIdx.x * 16;     // 6250*16 = 100000 exact
    const float sc0 = bn[tid], sc1 = bn[tid + 64];
    const float sh0 = bn[128 + tid], sh1 = bn[192 + tid];
    const float* hb = hpre + n0 * 128;
#pragma unroll
    for (int i = 0; i < 32; ++i) {
        int idx = tid + i * 64;        // column = tid (i even) or tid+64 (i odd)
        float v = hb[idx];
        float sc = (i & 1) ? sc1 : sc0;
        float sh = (i & 1) ? sh1 : sh0;
        v = fmaf(sc, v, sh);
        hs[idx] = v > 0.f ? v : 0.f;
    }
    __syncthreads();

    const float* wl = Wl + tid;   // column tid of Wl2 [128][64]
    const float* wr = Wr + tid;
    float accL[16], accR[16];
#pragma unroll
    for (int n = 0; n < 16; ++n) { accL[n] = 0.f; accR[n] = 0.f; }

    for (int k = 0; k < 128; k += 4) {
        float wl0 = wl[(k + 0) * 64], wl1 = wl[(k + 1) * 64], wl2 = wl[(k + 2) * 64], wl3 = wl[(k + 3) * 64];
        float wr0 = wr[(k + 0) * 64], wr1 = wr[(k + 1) * 64], wr2 = wr[(k + 2) * 64], wr3 = wr[(k + 3) * 64];
#pragma unroll
        for (int n = 0; n < 16; ++n) {
            float4 hv = *(const float4*)&hs[n * 128 + k];
            accL[n] = fmaf(hv.x, wl0, accL[n]);
            accL[n] = fmaf(hv.y, wl1, accL[n]);
            accL[n] = fmaf(hv.z, wl2, accL[n]);
            accL[n] = fmaf(hv.w, wl3, accL[n]);
            accR[n] = fmaf(hv.x, wr0, accR[n]);
            accR[n] = fmaf(hv.y, wr1, accR[n]);
            accR[n] = fmaf(hv.z, wr2, accR[n]);
            accR[n] = fmaf(hv.w, wr3, accR[n]);
        }
    }
    float* ob = t2r2 + n0 * 128;
#pragma unroll
    for (int n = 0; n < 16; ++n) {
        ob[n * 128 + tid] = accL[n];
        ob[n * 128 + 64 + tid] = accR[n];
    }
}

// ---------- layer 2 aggregate + bias -> out ----------
__global__ __launch_bounds__(64) void k_agg2(const float* __restrict__ t2r2, const int* __restrict__ rowptr,
                                             const int* __restrict__ ssrc, const float* __restrict__ b2,
                                             float* __restrict__ out) {
    const int tid = threadIdx.x;  // 0..63
    const int nbase = blockIdx.x * 16;             // 6250*16 = 100000 exact
    const float bias = b2[tid];
    for (int ni = 0; ni < 16; ++ni) {
        const int n = nbase + ni;
        const int lo = rowptr[n], hi = rowptr[n + 1];
        float a0 = 0.f, a1 = 0.f, a2 = 0.f, a3 = 0.f;
        int i = lo;
        for (; i + 4 <= hi; i += 4) {
            int s0 = ssrc[i], s1 = ssrc[i + 1], s2 = ssrc[i + 2], s3 = ssrc[i + 3];
            a0 += t2r2[(size_t)s0 * 128 + tid];
            a1 += t2r2[(size_t)s1 * 128 + tid];
            a2 += t2r2[(size_t)s2 * 128 + tid];
            a3 += t2r2[(size_t)s3 * 128 + tid];
        }
        for (; i < hi; ++i) a0 += t2r2[(size_t)ssrc[i] * 128 + tid];
        float acc = (a0 + a1) + (a2 + a3);
        float c = (float)(hi - lo);
        if (c < 1.f) c = 1.f;
        out[(size_t)n * 64 + tid] = acc / c + bias + t2r2[(size_t)n * 128 + 64 + tid];
    }
}

extern "C" void kernel_launch(void* const* d_in, const int* in_sizes, int n_in,
                              void* d_out, int out_size, void* d_ws, size_t ws_size,
                              hipStream_t stream) {
    const float* x      = (const float*)d_in[0];
    const int*   ei     = (const int*)d_in[1];
    const float* Wl1    = (const float*)d_in[2];
    const float* b1     = (const float*)d_in[3];
    const float* Wr1    = (const float*)d_in[4];
    const float* gamma1 = (const float*)d_in[5];
    const float* beta1  = (const float*)d_in[6];
    const float* Wl2    = (const float*)d_in[7];
    const float* b2     = (const float*)d_in[8];
    const float* Wr2    = (const float*)d_in[9];
    float* out = (float*)d_out;

    char* ws = (char*)d_ws;
    int*   rowptr = (int*)(ws + OFF_ROWPTR);
    int*   deg    = (int*)(ws + OFF_DEG);     // histogram, then scatter cursor
    float* bn     = (float*)(ws + OFF_BN);
    int*   ssrc   = (int*)(ws + OFF_SRC);
    float* t1r1   = (float*)(ws + OFF_T1R1);
    float* t2r2   = t1r1;                     // reuse: t1r1 dead after k_agg1
    float* hpre   = (float*)(ws + OFF_HPRE);
    int*   bsums  = (int*)(ws + OFF_T1R1);    // overlap: dead before k_gemm1 writes t1r1

    const int* esrc = ei;            // edge_index[0]
    const int* edst = ei + N_EDGES;  // edge_index[1]

    hipMemsetAsync(deg, 0, N_NODES * sizeof(int), stream);
    hipMemsetAsync(bn, 0, 256 * sizeof(float), stream);

    k_hist<<<N_EDGES / 256, 256, 0, stream>>>(edst, deg);
    k_scan_a<<<SCAN_NBLK, 1024, 0, stream>>>(deg, rowptr, bsums);
    k_scan_b<<<1, 128, 0, stream>>>(bsums);
    k_scan_c<<<SCAN_NBLK, 1024, 0, stream>>>(rowptr, deg, bsums);
    k_scatter<<<N_EDGES / 256, 256, 0, stream>>>(esrc, edst, deg, ssrc);

    k_gemm1<<<N_NODES / 16, 128, 0, stream>>>(x, Wl1, Wr1, t1r1);
    k_agg1<<<N_NODES / 32, 128, 0, stream>>>(t1r1, rowptr, ssrc, b1, hpre, bn);
    k_bnfin<<<1, 128, 0, stream>>>(bn, gamma1, beta1);
    k_gemm2<<<N_NODES / 16, 64, 0, stream>>>(hpre, bn, Wl2, Wr2, t2r2);
    k_agg2<<<N_NODES / 16, 64, 0, stream>>>(t2r2, rowptr, ssrc, b2, out);
}

// Round 4
// 564.542 us; speedup vs baseline: 1.4573x; 1.0645x over previous
//
#include <hip/hip_runtime.h>
#include <hip/hip_bf16.h>
#include <cstdint>
#include <cstddef>

#define N_NODES 100000
#define N_EDGES 1600000
#define EPSV 1e-5f

// ---- workspace layout (bytes) ----
// rowptr (N+1 int) @0 | deg/cursor (N int) @400384 | bn (256 f32) @800768
// ssrc (E int) @801792 | t1b (N*128 bf16) @7201792 | r1b (N*128 bf16) @32801792
// hpre (N*128 f32) @58401792 ... end 109601792
// t2b reuses t1b region (N*64 bf16); r2b reuses r1b region (N*64 bf16).
// bsums (98 int) overlaps t1b (dead before k_gemm1 writes).
#define OFF_ROWPTR 0
#define OFF_DEG    400384
#define OFF_BN     800768
#define OFF_SRC    801792
#define OFF_T1B    7201792
#define OFF_R1B    32801792
#define OFF_HPRE   58401792

#define SCAN_NBLK 98   // ceil(100000/1024)

__device__ __forceinline__ float bf2f(unsigned short u) {
    return __uint_as_float(((unsigned int)u) << 16);
}
__device__ __forceinline__ unsigned short f2bf(float f) {
    unsigned int u = __float_as_uint(f);
    u += 0x7fffu + ((u >> 16) & 1u);   // round-to-nearest-even
    return (unsigned short)(u >> 16);
}

// ---------- CSR build ----------
__global__ __launch_bounds__(256) void k_hist(const int* __restrict__ dst, int* __restrict__ deg) {
    int e = blockIdx.x * 256 + threadIdx.x;
    atomicAdd(&deg[dst[e]], 1);
}

__global__ __launch_bounds__(1024) void k_scan_a(const int* __restrict__ deg, int* __restrict__ rowptr,
                                                 int* __restrict__ bsums) {
    __shared__ int s[1024];
    const int t = threadIdx.x;
    const int i = blockIdx.x * 1024 + t;
    int v = (i < N_NODES) ? deg[i] : 0;
    s[t] = v;
    __syncthreads();
    for (int off = 1; off < 1024; off <<= 1) {
        int u = (t >= off) ? s[t - off] : 0;
        __syncthreads();
        s[t] += u;
        __syncthreads();
    }
    if (i < N_NODES) rowptr[i] = s[t] - v;
    if (t == 1023) bsums[blockIdx.x] = s[1023];
}

__global__ __launch_bounds__(128) void k_scan_b(int* __restrict__ bsums) {
    __shared__ int s[128];
    const int t = threadIdx.x;
    int v = (t < SCAN_NBLK) ? bsums[t] : 0;
    s[t] = v;
    __syncthreads();
    for (int off = 1; off < 128; off <<= 1) {
        int u = (t >= off) ? s[t - off] : 0;
        __syncthreads();
        s[t] += u;
        __syncthreads();
    }
    if (t < SCAN_NBLK) bsums[t] = s[t] - v;
}

__global__ __launch_bounds__(1024) void k_scan_c(int* __restrict__ rowptr, int* __restrict__ cursor,
                                                 const int* __restrict__ bsums) {
    const int i = blockIdx.x * 1024 + threadIdx.x;
    if (i < N_NODES) {
        int r = rowptr[i] + bsums[blockIdx.x];
        rowptr[i] = r;
        cursor[i] = r;
    }
    if (i == N_NODES) rowptr[N_NODES] = N_EDGES;
}

__global__ __launch_bounds__(256) void k_scatter(const int* __restrict__ src, const int* __restrict__ dst,
                                                 int* __restrict__ cursor, int* __restrict__ ssrc) {
    int e = blockIdx.x * 256 + threadIdx.x;
    int d = dst[e];
    int pos = atomicAdd(&cursor[d], 1);
    ssrc[pos] = src[e];
}

// ---------- layer 1 GEMM: t1b|r1b = bf16(x @ [Wl1 | Wr1]) ----------
__global__ __launch_bounds__(128) void k_gemm1(const float* __restrict__ x, const float* __restrict__ Wl,
                                               const float* __restrict__ Wr,
                                               unsigned short* __restrict__ t1b,
                                               unsigned short* __restrict__ r1b) {
    __shared__ float xs[16 * 128];
    const int tid = threadIdx.x;
    const size_t n0 = (size_t)blockIdx.x * 16;     // 6250*16 = 100000
    const float* xb = x + n0 * 128;
#pragma unroll
    for (int i = 0; i < 16; ++i) xs[tid + i * 128] = xb[tid + i * 128];
    __syncthreads();

    const float* wl = Wl + tid;
    const float* wr = Wr + tid;
    float accL[16], accR[16];
#pragma unroll
    for (int n = 0; n < 16; ++n) { accL[n] = 0.f; accR[n] = 0.f; }

    for (int k = 0; k < 128; k += 4) {
        float wl0 = wl[(k + 0) * 128], wl1 = wl[(k + 1) * 128], wl2 = wl[(k + 2) * 128], wl3 = wl[(k + 3) * 128];
        float wr0 = wr[(k + 0) * 128], wr1 = wr[(k + 1) * 128], wr2 = wr[(k + 2) * 128], wr3 = wr[(k + 3) * 128];
#pragma unroll
        for (int n = 0; n < 16; ++n) {
            float4 xv = *(const float4*)&xs[n * 128 + k];
            accL[n] = fmaf(xv.x, wl0, accL[n]);
            accL[n] = fmaf(xv.y, wl1, accL[n]);
            accL[n] = fmaf(xv.z, wl2, accL[n]);
            accL[n] = fmaf(xv.w, wl3, accL[n]);
            accR[n] = fmaf(xv.x, wr0, accR[n]);
            accR[n] = fmaf(xv.y, wr1, accR[n]);
            accR[n] = fmaf(xv.z, wr2, accR[n]);
            accR[n] = fmaf(xv.w, wr3, accR[n]);
        }
    }
    unsigned short* tb = t1b + n0 * 128;
    unsigned short* rb = r1b + n0 * 128;
#pragma unroll
    for (int n = 0; n < 16; ++n) {
        tb[n * 128 + tid] = f2bf(accL[n]);
        rb[n * 128 + tid] = f2bf(accR[n]);
    }
}

// ---------- layer 1 aggregate + bias + BN partials ----------
__global__ __launch_bounds__(128) void k_agg1(const unsigned short* __restrict__ t1b,
                                              const unsigned short* __restrict__ r1b,
                                              const int* __restrict__ rowptr,
                                              const int* __restrict__ ssrc, const float* __restrict__ b1,
                                              float* __restrict__ hpre, float* __restrict__ bn) {
    const int tid = threadIdx.x;
    const int nbase = blockIdx.x * 32;             // 3125*32 = 100000
    const float bias = b1[tid];
    float bsum = 0.f, bsq = 0.f;
    for (int ni = 0; ni < 32; ++ni) {
        const int n = nbase + ni;
        const int lo = rowptr[n], hi = rowptr[n + 1];
        float a0 = 0.f, a1 = 0.f, a2 = 0.f, a3 = 0.f;
        int i = lo;
        for (; i + 4 <= hi; i += 4) {
            int s0 = ssrc[i], s1 = ssrc[i + 1], s2 = ssrc[i + 2], s3 = ssrc[i + 3];
            a0 += bf2f(t1b[(size_t)s0 * 128 + tid]);
            a1 += bf2f(t1b[(size_t)s1 * 128 + tid]);
            a2 += bf2f(t1b[(size_t)s2 * 128 + tid]);
            a3 += bf2f(t1b[(size_t)s3 * 128 + tid]);
        }
        for (; i < hi; ++i) a0 += bf2f(t1b[(size_t)ssrc[i] * 128 + tid]);
        float acc = (a0 + a1) + (a2 + a3);
        float c = (float)(hi - lo);
        if (c < 1.f) c = 1.f;
        float v = acc / c + bias + bf2f(r1b[(size_t)n * 128 + tid]);
        hpre[(size_t)n * 128 + tid] = v;
        bsum += v;
        bsq += v * v;
    }
    atomicAdd(&bn[tid], bsum);
    atomicAdd(&bn[128 + tid], bsq);
}

// ---------- BN finalize ----------
__global__ void k_bnfin(float* __restrict__ bn, const float* __restrict__ gamma, const float* __restrict__ beta) {
    int f = threadIdx.x;  // 128
    float mean = bn[f] * (1.0f / N_NODES);
    float var = bn[128 + f] * (1.0f / N_NODES) - mean * mean;
    float sc = gamma[f] * rsqrtf(var + EPSV);
    bn[f] = sc;
    bn[128 + f] = beta[f] - mean * sc;
}

// ---------- layer 2 GEMM with fused BN+ReLU ----------
__global__ __launch_bounds__(64) void k_gemm2(const float* __restrict__ hpre, const float* __restrict__ bn,
                                              const float* __restrict__ Wl, const float* __restrict__ Wr,
                                              unsigned short* __restrict__ t2b,
                                              unsigned short* __restrict__ r2b) {
    __shared__ float hs[16 * 128];
    const int tid = threadIdx.x;  // 0..63
    const size_t n0 = (size_t)blockIdx.x * 16;
    const float sc0 = bn[tid], sc1 = bn[tid + 64];
    const float sh0 = bn[128 + tid], sh1 = bn[192 + tid];
    const float* hb = hpre + n0 * 128;
#pragma unroll
    for (int i = 0; i < 32; ++i) {
        int idx = tid + i * 64;
        float v = hb[idx];
        float sc = (i & 1) ? sc1 : sc0;
        float sh = (i & 1) ? sh1 : sh0;
        v = fmaf(sc, v, sh);
        hs[idx] = v > 0.f ? v : 0.f;
    }
    __syncthreads();

    const float* wl = Wl + tid;
    const float* wr = Wr + tid;
    float accL[16], accR[16];
#pragma unroll
    for (int n = 0; n < 16; ++n) { accL[n] = 0.f; accR[n] = 0.f; }

    for (int k = 0; k < 128; k += 4) {
        float wl0 = wl[(k + 0) * 64], wl1 = wl[(k + 1) * 64], wl2 = wl[(k + 2) * 64], wl3 = wl[(k + 3) * 64];
        float wr0 = wr[(k + 0) * 64], wr1 = wr[(k + 1) * 64], wr2 = wr[(k + 2) * 64], wr3 = wr[(k + 3) * 64];
#pragma unroll
        for (int n = 0; n < 16; ++n) {
            float4 hv = *(const float4*)&hs[n * 128 + k];
            accL[n] = fmaf(hv.x, wl0, accL[n]);
            accL[n] = fmaf(hv.y, wl1, accL[n]);
            accL[n] = fmaf(hv.z, wl2, accL[n]);
            accL[n] = fmaf(hv.w, wl3, accL[n]);
            accR[n] = fmaf(hv.x, wr0, accR[n]);
            accR[n] = fmaf(hv.y, wr1, accR[n]);
            accR[n] = fmaf(hv.z, wr2, accR[n]);
            accR[n] = fmaf(hv.w, wr3, accR[n]);
        }
    }
    unsigned short* tb = t2b + n0 * 64;
    unsigned short* rb = r2b + n0 * 64;
#pragma unroll
    for (int n = 0; n < 16; ++n) {
        tb[n * 64 + tid] = f2bf(accL[n]);
        rb[n * 64 + tid] = f2bf(accR[n]);
    }
}

// ---------- layer 2 aggregate + bias -> out ----------
__global__ __launch_bounds__(64) void k_agg2(const unsigned short* __restrict__ t2b,
                                             const unsigned short* __restrict__ r2b,
                                             const int* __restrict__ rowptr,
                                             const int* __restrict__ ssrc, const float* __restrict__ b2,
                                             float* __restrict__ out) {
    const int tid = threadIdx.x;  // 0..63
    const int nbase = blockIdx.x * 16;
    const float bias = b2[tid];
    for (int ni = 0; ni < 16; ++ni) {
        const int n = nbase + ni;
        const int lo = rowptr[n], hi = rowptr[n + 1];
        float a0 = 0.f, a1 = 0.f, a2 = 0.f, a3 = 0.f;
        int i = lo;
        for (; i + 4 <= hi; i += 4) {
            int s0 = ssrc[i], s1 = ssrc[i + 1], s2 = ssrc[i + 2], s3 = ssrc[i + 3];
            a0 += bf2f(t2b[(size_t)s0 * 64 + tid]);
            a1 += bf2f(t2b[(size_t)s1 * 64 + tid]);
            a2 += bf2f(t2b[(size_t)s2 * 64 + tid]);
            a3 += bf2f(t2b[(size_t)s3 * 64 + tid]);
        }
        for (; i < hi; ++i) a0 += bf2f(t2b[(size_t)ssrc[i] * 64 + tid]);
        float acc = (a0 + a1) + (a2 + a3);
        float c = (float)(hi - lo);
        if (c < 1.f) c = 1.f;
        out[(size_t)n * 64 + tid] = acc / c + bias + bf2f(r2b[(size_t)n * 64 + tid]);
    }
}

extern "C" void kernel_launch(void* const* d_in, const int* in_sizes, int n_in,
                              void* d_out, int out_size, void* d_ws, size_t ws_size,
                              hipStream_t stream) {
    const float* x      = (const float*)d_in[0];
    const int*   ei     = (const int*)d_in[1];
    const float* Wl1    = (const float*)d_in[2];
    const float* b1     = (const float*)d_in[3];
    const float* Wr1    = (const float*)d_in[4];
    const float* gamma1 = (const float*)d_in[5];
    const float* beta1  = (const float*)d_in[6];
    const float* Wl2    = (const float*)d_in[7];
    const float* b2     = (const float*)d_in[8];
    const float* Wr2    = (const float*)d_in[9];
    float* out = (float*)d_out;

    char* ws = (char*)d_ws;
    int*            rowptr = (int*)(ws + OFF_ROWPTR);
    int*            deg    = (int*)(ws + OFF_DEG);
    float*          bn     = (float*)(ws + OFF_BN);
    int*            ssrc   = (int*)(ws + OFF_SRC);
    unsigned short* t1b    = (unsigned short*)(ws + OFF_T1B);
    unsigned short* r1b    = (unsigned short*)(ws + OFF_R1B);
    float*          hpre   = (float*)(ws + OFF_HPRE);
    unsigned short* t2b    = t1b;   // reuse: dead after k_agg1
    unsigned short* r2b    = r1b;   // reuse: dead after k_agg1
    int*            bsums  = (int*)(ws + OFF_T1B);  // dead before k_gemm1

    const int* esrc = ei;
    const int* edst = ei + N_EDGES;

    hipMemsetAsync(deg, 0, N_NODES * sizeof(int), stream);
    hipMemsetAsync(bn, 0, 256 * sizeof(float), stream);

    k_hist<<<N_EDGES / 256, 256, 0, stream>>>(edst, deg);
    k_scan_a<<<SCAN_NBLK, 1024, 0, stream>>>(deg, rowptr, bsums);
    k_scan_b<<<1, 128, 0, stream>>>(bsums);
    k_scan_c<<<SCAN_NBLK, 1024, 0, stream>>>(rowptr, deg, bsums);
    k_scatter<<<N_EDGES / 256, 256, 0, stream>>>(esrc, edst, deg, ssrc);

    k_gemm1<<<N_NODES / 16, 128, 0, stream>>>(x, Wl1, Wr1, t1b, r1b);
    k_agg1<<<N_NODES / 32, 128, 0, stream>>>(t1b, r1b, rowptr, ssrc, b1, hpre, bn);
    k_bnfin<<<1, 128, 0, stream>>>(bn, gamma1, beta1);
    k_gemm2<<<N_NODES / 16, 64, 0, stream>>>(hpre, bn, Wl2, Wr2, t2b, r2b);
    k_agg2<<<N_NODES / 16, 64, 0, stream>>>(t2b, r2b, rowptr, ssrc, b2, out);
}

// Round 5
// 519.930 us; speedup vs baseline: 1.5823x; 1.0858x over previous
//
#include <hip/hip_runtime.h>
#include <hip/hip_bf16.h>
#include <cstdint>
#include <cstddef>

#define N_NODES 100000
#define N_EDGES 1600000
#define EPSV 1e-5f

// ---- workspace layout (bytes) ----
#define OFF_ROWPTR 0
#define OFF_DEG    400384
#define OFF_BN     800768
#define OFF_SRC    801792
#define OFF_T1B    7201792
#define OFF_R1B    32801792
#define OFF_HPRE   58401792

#define SCAN_NBLK 98   // ceil(100000/1024)
#define GEMM1_NBLK 6250
#define HIST_NBLK  12500   // 1.6M / 128

__device__ __forceinline__ float bf2f(unsigned short u) {
    return __uint_as_float(((unsigned int)u) << 16);
}
__device__ __forceinline__ float bf2f_lo(unsigned int u) {
    return __uint_as_float(u << 16);
}
__device__ __forceinline__ float bf2f_hi(unsigned int u) {
    return __uint_as_float(u & 0xffff0000u);
}
__device__ __forceinline__ unsigned short f2bf(float f) {
    unsigned int u = __float_as_uint(f);
    u += 0x7fffu + ((u >> 16) & 1u);   // round-to-nearest-even
    return (unsigned short)(u >> 16);
}

// ---------- CSR scan ----------
__global__ __launch_bounds__(1024) void k_scan_a(const int* __restrict__ deg, int* __restrict__ rowptr,
                                                 int* __restrict__ bsums) {
    __shared__ int s[1024];
    const int t = threadIdx.x;
    const int i = blockIdx.x * 1024 + t;
    int v = (i < N_NODES) ? deg[i] : 0;
    s[t] = v;
    __syncthreads();
    for (int off = 1; off < 1024; off <<= 1) {
        int u = (t >= off) ? s[t - off] : 0;
        __syncthreads();
        s[t] += u;
        __syncthreads();
    }
    if (i < N_NODES) rowptr[i] = s[t] - v;
    if (t == 1023) bsums[blockIdx.x] = s[1023];
}

__global__ __launch_bounds__(128) void k_scan_b(int* __restrict__ bsums) {
    __shared__ int s[128];
    const int t = threadIdx.x;
    int v = (t < SCAN_NBLK) ? bsums[t] : 0;
    s[t] = v;
    __syncthreads();
    for (int off = 1; off < 128; off <<= 1) {
        int u = (t >= off) ? s[t - off] : 0;
        __syncthreads();
        s[t] += u;
        __syncthreads();
    }
    if (t < SCAN_NBLK) bsums[t] = s[t] - v;
}

__global__ __launch_bounds__(1024) void k_scan_c(int* __restrict__ rowptr, int* __restrict__ cursor,
                                                 const int* __restrict__ bsums) {
    const int i = blockIdx.x * 1024 + threadIdx.x;
    if (i < N_NODES) {
        int r = rowptr[i] + bsums[blockIdx.x];
        rowptr[i] = r;
        cursor[i] = r;
    }
    if (i == N_NODES) rowptr[N_NODES] = N_EDGES;
}

__global__ __launch_bounds__(256) void k_scatter(const int* __restrict__ src, const int* __restrict__ dst,
                                                 int* __restrict__ cursor, int* __restrict__ ssrc) {
    int e = blockIdx.x * 256 + threadIdx.x;
    int d = dst[e];
    int pos = atomicAdd(&cursor[d], 1);
    ssrc[pos] = src[e];
}

// ---------- fused: layer-1 GEMM (blocks 0..6249) + degree histogram (blocks 6250..18749) ----------
__global__ __launch_bounds__(128) void k_gemm1h(const float* __restrict__ x, const float* __restrict__ Wl,
                                                const float* __restrict__ Wr,
                                                unsigned short* __restrict__ t1b,
                                                unsigned short* __restrict__ r1b,
                                                const int* __restrict__ dst, int* __restrict__ deg) {
    if (blockIdx.x >= GEMM1_NBLK) {
        int e = (blockIdx.x - GEMM1_NBLK) * 128 + threadIdx.x;   // exactly covers E
        atomicAdd(&deg[dst[e]], 1);
        return;
    }
    __shared__ float xs[16 * 128];
    const int tid = threadIdx.x;
    const size_t n0 = (size_t)blockIdx.x * 16;
    const float* xb = x + n0 * 128;
#pragma unroll
    for (int i = 0; i < 16; ++i) xs[tid + i * 128] = xb[tid + i * 128];
    __syncthreads();

    const float* wl = Wl + tid;
    const float* wr = Wr + tid;
    float accL[16], accR[16];
#pragma unroll
    for (int n = 0; n < 16; ++n) { accL[n] = 0.f; accR[n] = 0.f; }

    for (int k = 0; k < 128; k += 4) {
        float wl0 = wl[(k + 0) * 128], wl1 = wl[(k + 1) * 128], wl2 = wl[(k + 2) * 128], wl3 = wl[(k + 3) * 128];
        float wr0 = wr[(k + 0) * 128], wr1 = wr[(k + 1) * 128], wr2 = wr[(k + 2) * 128], wr3 = wr[(k + 3) * 128];
#pragma unroll
        for (int n = 0; n < 16; ++n) {
            float4 xv = *(const float4*)&xs[n * 128 + k];
            accL[n] = fmaf(xv.x, wl0, accL[n]);
            accL[n] = fmaf(xv.y, wl1, accL[n]);
            accL[n] = fmaf(xv.z, wl2, accL[n]);
            accL[n] = fmaf(xv.w, wl3, accL[n]);
            accR[n] = fmaf(xv.x, wr0, accR[n]);
            accR[n] = fmaf(xv.y, wr1, accR[n]);
            accR[n] = fmaf(xv.z, wr2, accR[n]);
            accR[n] = fmaf(xv.w, wr3, accR[n]);
        }
    }
    unsigned short* tb = t1b + n0 * 128;
    unsigned short* rb = r1b + n0 * 128;
#pragma unroll
    for (int n = 0; n < 16; ++n) {
        tb[n * 128 + tid] = f2bf(accL[n]);
        rb[n * 128 + tid] = f2bf(accR[n]);
    }
}

// ---------- layer 1 aggregate: one row per wave, ushort2 per lane, 8-deep unroll ----------
__global__ __launch_bounds__(256) void k_agg1(const unsigned short* __restrict__ t1b,
                                              const unsigned short* __restrict__ r1b,
                                              const int* __restrict__ rowptr,
                                              const int* __restrict__ ssrc, const float* __restrict__ b1,
                                              float* __restrict__ hpre, float* __restrict__ bn) {
    const int wv = threadIdx.x >> 6;       // wave 0..3
    const int l  = threadIdx.x & 63;       // lane
    const int nbase = blockIdx.x * 32;     // 3125 blocks * 32 rows
    const float bias0 = b1[2 * l], bias1 = b1[2 * l + 1];
    float sa0 = 0.f, sa1 = 0.f, sq0 = 0.f, sq1 = 0.f;

    for (int r = wv; r < 32; r += 4) {
        const int n = nbase + r;
        const int lo = rowptr[n], hi = rowptr[n + 1];
        float a0 = 0.f, a1 = 0.f, b0 = 0.f, b1f = 0.f;
        int i = lo;
        for (; i + 8 <= hi; i += 8) {
            int s0 = ssrc[i], s1 = ssrc[i + 1], s2 = ssrc[i + 2], s3 = ssrc[i + 3];
            int s4 = ssrc[i + 4], s5 = ssrc[i + 5], s6 = ssrc[i + 6], s7 = ssrc[i + 7];
            unsigned int u0 = *(const unsigned int*)&t1b[(size_t)s0 * 128 + 2 * l];
            unsigned int u1 = *(const unsigned int*)&t1b[(size_t)s1 * 128 + 2 * l];
            unsigned int u2 = *(const unsigned int*)&t1b[(size_t)s2 * 128 + 2 * l];
            unsigned int u3 = *(const unsigned int*)&t1b[(size_t)s3 * 128 + 2 * l];
            unsigned int u4 = *(const unsigned int*)&t1b[(size_t)s4 * 128 + 2 * l];
            unsigned int u5 = *(const unsigned int*)&t1b[(size_t)s5 * 128 + 2 * l];
            unsigned int u6 = *(const unsigned int*)&t1b[(size_t)s6 * 128 + 2 * l];
            unsigned int u7 = *(const unsigned int*)&t1b[(size_t)s7 * 128 + 2 * l];
            a0 += bf2f_lo(u0) + bf2f_lo(u1); a1 += bf2f_hi(u0) + bf2f_hi(u1);
            b0 += bf2f_lo(u2) + bf2f_lo(u3); b1f += bf2f_hi(u2) + bf2f_hi(u3);
            a0 += bf2f_lo(u4) + bf2f_lo(u5); a1 += bf2f_hi(u4) + bf2f_hi(u5);
            b0 += bf2f_lo(u6) + bf2f_lo(u7); b1f += bf2f_hi(u6) + bf2f_hi(u7);
        }
        for (; i < hi; ++i) {
            unsigned int u = *(const unsigned int*)&t1b[(size_t)ssrc[i] * 128 + 2 * l];
            a0 += bf2f_lo(u); a1 += bf2f_hi(u);
        }
        float c = (float)(hi - lo);
        if (c < 1.f) c = 1.f;
        float inv = 1.0f / c;
        unsigned int ur = *(const unsigned int*)&r1b[(size_t)n * 128 + 2 * l];
        float v0 = (a0 + b0) * inv + bias0 + bf2f_lo(ur);
        float v1 = (a1 + b1f) * inv + bias1 + bf2f_hi(ur);
        *(float2*)&hpre[(size_t)n * 128 + 2 * l] = make_float2(v0, v1);
        sa0 += v0; sa1 += v1; sq0 += v0 * v0; sq1 += v1 * v1;
    }

    // cross-wave reduce BN partials in LDS, then 1 atomic per feature per block
    __shared__ float red[2][4][128];
    red[0][wv][2 * l] = sa0; red[0][wv][2 * l + 1] = sa1;
    red[1][wv][2 * l] = sq0; red[1][wv][2 * l + 1] = sq1;
    __syncthreads();
    int t = threadIdx.x;
    if (t < 128) {
        atomicAdd(&bn[t], red[0][0][t] + red[0][1][t] + red[0][2][t] + red[0][3][t]);
    } else {
        int f = t - 128;
        atomicAdd(&bn[128 + f], red[1][0][f] + red[1][1][f] + red[1][2][f] + red[1][3][f]);
    }
}

// ---------- BN finalize ----------
__global__ void k_bnfin(float* __restrict__ bn, const float* __restrict__ gamma, const float* __restrict__ beta) {
    int f = threadIdx.x;  // 128
    float mean = bn[f] * (1.0f / N_NODES);
    float var = bn[128 + f] * (1.0f / N_NODES) - mean * mean;
    float sc = gamma[f] * rsqrtf(var + EPSV);
    bn[f] = sc;
    bn[128 + f] = beta[f] - mean * sc;
}

// ---------- layer 2 GEMM with fused BN+ReLU ----------
__global__ __launch_bounds__(64) void k_gemm2(const float* __restrict__ hpre, const float* __restrict__ bn,
                                              const float* __restrict__ Wl, const float* __restrict__ Wr,
                                              unsigned short* __restrict__ t2b,
                                              unsigned short* __restrict__ r2b) {
    __shared__ float hs[16 * 128];
    const int tid = threadIdx.x;  // 0..63
    const size_t n0 = (size_t)blockIdx.x * 16;
    const float sc0 = bn[tid], sc1 = bn[tid + 64];
    const float sh0 = bn[128 + tid], sh1 = bn[192 + tid];
    const float* hb = hpre + n0 * 128;
#pragma unroll
    for (int i = 0; i < 32; ++i) {
        int idx = tid + i * 64;
        float v = hb[idx];
        float sc = (i & 1) ? sc1 : sc0;
        float sh = (i & 1) ? sh1 : sh0;
        v = fmaf(sc, v, sh);
        hs[idx] = v > 0.f ? v : 0.f;
    }
    __syncthreads();

    const float* wl = Wl + tid;
    const float* wr = Wr + tid;
    float accL[16], accR[16];
#pragma unroll
    for (int n = 0; n < 16; ++n) { accL[n] = 0.f; accR[n] = 0.f; }

    for (int k = 0; k < 128; k += 4) {
        float wl0 = wl[(k + 0) * 64], wl1 = wl[(k + 1) * 64], wl2 = wl[(k + 2) * 64], wl3 = wl[(k + 3) * 64];
        float wr0 = wr[(k + 0) * 64], wr1 = wr[(k + 1) * 64], wr2 = wr[(k + 2) * 64], wr3 = wr[(k + 3) * 64];
#pragma unroll
        for (int n = 0; n < 16; ++n) {
            float4 hv = *(const float4*)&hs[n * 128 + k];
            accL[n] = fmaf(hv.x, wl0, accL[n]);
            accL[n] = fmaf(hv.y, wl1, accL[n]);
            accL[n] = fmaf(hv.z, wl2, accL[n]);
            accL[n] = fmaf(hv.w, wl3, accL[n]);
            accR[n] = fmaf(hv.x, wr0, accR[n]);
            accR[n] = fmaf(hv.y, wr1, accR[n]);
            accR[n] = fmaf(hv.z, wr2, accR[n]);
            accR[n] = fmaf(hv.w, wr3, accR[n]);
        }
    }
    unsigned short* tb = t2b + n0 * 64;
    unsigned short* rb = r2b + n0 * 64;
#pragma unroll
    for (int n = 0; n < 16; ++n) {
        tb[n * 64 + tid] = f2bf(accL[n]);
        rb[n * 64 + tid] = f2bf(accR[n]);
    }
}

// ---------- layer 2 aggregate: one row per wave, ushort per lane, 8-deep unroll ----------
__global__ __launch_bounds__(256) void k_agg2(const unsigned short* __restrict__ t2b,
                                              const unsigned short* __restrict__ r2b,
                                              const int* __restrict__ rowptr,
                                              const int* __restrict__ ssrc, const float* __restrict__ b2,
                                              float* __restrict__ out) {
    const int wv = threadIdx.x >> 6;
    const int l  = threadIdx.x & 63;
    const int nbase = blockIdx.x * 16;     // 6250 blocks * 16 rows
    const float bias = b2[l];

    for (int r = wv; r < 16; r += 4) {
        const int n = nbase + r;
        const int lo = rowptr[n], hi = rowptr[n + 1];
        float a0 = 0.f, a1 = 0.f;
        int i = lo;
        for (; i + 8 <= hi; i += 8) {
            int s0 = ssrc[i], s1 = ssrc[i + 1], s2 = ssrc[i + 2], s3 = ssrc[i + 3];
            int s4 = ssrc[i + 4], s5 = ssrc[i + 5], s6 = ssrc[i + 6], s7 = ssrc[i + 7];
            float f0 = bf2f(t2b[(size_t)s0 * 64 + l]);
            float f1 = bf2f(t2b[(size_t)s1 * 64 + l]);
            float f2 = bf2f(t2b[(size_t)s2 * 64 + l]);
            float f3 = bf2f(t2b[(size_t)s3 * 64 + l]);
            float f4 = bf2f(t2b[(size_t)s4 * 64 + l]);
            float f5 = bf2f(t2b[(size_t)s5 * 64 + l]);
            float f6 = bf2f(t2b[(size_t)s6 * 64 + l]);
            float f7 = bf2f(t2b[(size_t)s7 * 64 + l]);
            a0 += (f0 + f1) + (f2 + f3);
            a1 += (f4 + f5) + (f6 + f7);
        }
        for (; i < hi; ++i) a0 += bf2f(t2b[(size_t)ssrc[i] * 64 + l]);
        float c = (float)(hi - lo);
        if (c < 1.f) c = 1.f;
        out[(size_t)n * 64 + l] = (a0 + a1) / c + bias + bf2f(r2b[(size_t)n * 64 + l]);
    }
}

extern "C" void kernel_launch(void* const* d_in, const int* in_sizes, int n_in,
                              void* d_out, int out_size, void* d_ws, size_t ws_size,
                              hipStream_t stream) {
    const float* x      = (const float*)d_in[0];
    const int*   ei     = (const int*)d_in[1];
    const float* Wl1    = (const float*)d_in[2];
    const float* b1     = (const float*)d_in[3];
    const float* Wr1    = (const float*)d_in[4];
    const float* gamma1 = (const float*)d_in[5];
    const float* beta1  = (const float*)d_in[6];
    const float* Wl2    = (const float*)d_in[7];
    const float* b2     = (const float*)d_in[8];
    const float* Wr2    = (const float*)d_in[9];
    float* out = (float*)d_out;

    char* ws = (char*)d_ws;
    int*            rowptr = (int*)(ws + OFF_ROWPTR);
    int*            deg    = (int*)(ws + OFF_DEG);
    float*          bn     = (float*)(ws + OFF_BN);
    int*            ssrc   = (int*)(ws + OFF_SRC);
    unsigned short* t1b    = (unsigned short*)(ws + OFF_T1B);
    unsigned short* r1b    = (unsigned short*)(ws + OFF_R1B);
    float*          hpre   = (float*)(ws + OFF_HPRE);
    unsigned short* t2b    = t1b;   // reuse: dead after k_agg1
    unsigned short* r2b    = r1b;   // reuse: dead after k_agg1
    int*            bsums  = (int*)(ws + OFF_DEG + N_NODES * sizeof(int) - SCAN_NBLK * sizeof(int)); // tail of deg? NO
    // bsums must not alias deg (scan reads deg). Place bsums in the t2-dead zone is unsafe now
    // (t1b written by fused kernel BEFORE scans run). Use the gap after bn (801792-801792?) -> put after ssrc.
    bsums = (int*)(ws + OFF_SRC + N_EDGES * sizeof(int));   // 801792+6400000=7201792 == OFF_T1B. Conflict!
    // Safe spot: bn region is 256 floats at 800768, 1024 bytes; ssrc starts 801792. bn occupies exactly it.
    // Use hpre region start for bsums: hpre is written only by k_agg1 (after scans complete).
    bsums = (int*)(ws + OFF_HPRE);

    const int* esrc = ei;
    const int* edst = ei + N_EDGES;

    hipMemsetAsync(deg, 0, N_NODES * sizeof(int), stream);
    hipMemsetAsync(bn, 0, 256 * sizeof(float), stream);

    k_gemm1h<<<GEMM1_NBLK + HIST_NBLK, 128, 0, stream>>>(x, Wl1, Wr1, t1b, r1b, edst, deg);
    k_scan_a<<<SCAN_NBLK, 1024, 0, stream>>>(deg, rowptr, bsums);
    k_scan_b<<<1, 128, 0, stream>>>(bsums);
    k_scan_c<<<SCAN_NBLK, 1024, 0, stream>>>(rowptr, deg, bsums);
    k_scatter<<<N_EDGES / 256, 256, 0, stream>>>(esrc, edst, deg, ssrc);

    k_agg1<<<N_NODES / 32, 256, 0, stream>>>(t1b, r1b, rowptr, ssrc, b1, hpre, bn);
    k_bnfin<<<1, 128, 0, stream>>>(bn, gamma1, beta1);
    k_gemm2<<<N_NODES / 16, 64, 0, stream>>>(hpre, bn, Wl2, Wr2, t2b, r2b);
    k_agg2<<<N_NODES / 16, 256, 0, stream>>>(t2b, r2b, rowptr, ssrc, b2, out);
}

// Round 6
// 445.732 us; speedup vs baseline: 1.8457x; 1.1665x over previous
//
#include <hip/hip_runtime.h>
#include <hip/hip_bf16.h>
#include <cstdint>
#include <cstddef>

#define N_NODES 100000
#define N_EDGES 1600000
#define EPSV 1e-5f

// ---- workspace layout (bytes) ----
#define OFF_ROWPTR 0
#define OFF_DEG    400384
#define OFF_BN     800768
#define OFF_SRC    801792
#define OFF_T1B    7201792
#define OFF_R1B    32801792
#define OFF_HPRE   58401792

#define SCAN_NBLK 98      // ceil(100000/1024)
#define GEMM_MBLK 3125    // 100000/32 row-tiles
#define HIST_NBLK 625     // 625*256*10 = 1.6M edges

typedef short v8s __attribute__((ext_vector_type(8)));
typedef float v4f __attribute__((ext_vector_type(4)));

__device__ __forceinline__ float bf2f(unsigned short u) {
    return __uint_as_float(((unsigned int)u) << 16);
}
__device__ __forceinline__ float bf2f_lo(unsigned int u) {
    return __uint_as_float(u << 16);
}
__device__ __forceinline__ float bf2f_hi(unsigned int u) {
    return __uint_as_float(u & 0xffff0000u);
}
__device__ __forceinline__ unsigned short f2bf(float f) {
    unsigned int u = __float_as_uint(f);
    u += 0x7fffu + ((u >> 16) & 1u);   // round-to-nearest-even
    return (unsigned short)(u >> 16);
}
__device__ __forceinline__ unsigned int pk2(float a, float b) {
    return (unsigned int)f2bf(a) | ((unsigned int)f2bf(b) << 16);
}

// ---------- CSR scan ----------
__global__ __launch_bounds__(1024) void k_scan_a(const int* __restrict__ deg, int* __restrict__ rowptr,
                                                 int* __restrict__ bsums) {
    __shared__ int s[1024];
    const int t = threadIdx.x;
    const int i = blockIdx.x * 1024 + t;
    int v = (i < N_NODES) ? deg[i] : 0;
    s[t] = v;
    __syncthreads();
    for (int off = 1; off < 1024; off <<= 1) {
        int u = (t >= off) ? s[t - off] : 0;
        __syncthreads();
        s[t] += u;
        __syncthreads();
    }
    if (i < N_NODES) rowptr[i] = s[t] - v;
    if (t == 1023) bsums[blockIdx.x] = s[1023];
}

__global__ __launch_bounds__(128) void k_scan_b(int* __restrict__ bsums) {
    __shared__ int s[128];
    const int t = threadIdx.x;
    int v = (t < SCAN_NBLK) ? bsums[t] : 0;
    s[t] = v;
    __syncthreads();
    for (int off = 1; off < 128; off <<= 1) {
        int u = (t >= off) ? s[t - off] : 0;
        __syncthreads();
        s[t] += u;
        __syncthreads();
    }
    if (t < SCAN_NBLK) bsums[t] = s[t] - v;
}

__global__ __launch_bounds__(1024) void k_scan_c(int* __restrict__ rowptr, int* __restrict__ cursor,
                                                 const int* __restrict__ bsums) {
    const int i = blockIdx.x * 1024 + threadIdx.x;
    if (i < N_NODES) {
        int r = rowptr[i] + bsums[blockIdx.x];
        rowptr[i] = r;
        cursor[i] = r;
    }
    if (i == N_NODES) rowptr[N_NODES] = N_EDGES;
}

__global__ __launch_bounds__(256) void k_scatter(const int* __restrict__ src, const int* __restrict__ dst,
                                                 int* __restrict__ cursor, int* __restrict__ ssrc) {
    int e = blockIdx.x * 256 + threadIdx.x;
    int d = dst[e];
    int pos = atomicAdd(&cursor[d], 1);
    ssrc[pos] = src[e];
}

// ---------- fused: degree histogram (blocks 0..624) + layer-1 MFMA GEMM ----------
// GEMM blocks: id = bid-625; half = id/3125 (0 -> t1b via Wl1, 1 -> r1b via Wr1); blk = id%3125.
// Each GEMM block: 32 rows x 128 cols, K=128. bf16 MFMA 16x16x32 with XOR-swizzled LDS.
__global__ __launch_bounds__(256) void k_gemm1h(const float* __restrict__ x, const float* __restrict__ Wl,
                                                const float* __restrict__ Wr,
                                                unsigned short* __restrict__ t1b,
                                                unsigned short* __restrict__ r1b,
                                                const int* __restrict__ dst, int* __restrict__ deg) {
    const int t = threadIdx.x;
    if (blockIdx.x < HIST_NBLK) {
        int base = blockIdx.x * 2560 + t;
#pragma unroll
        for (int i = 0; i < 10; ++i) atomicAdd(&deg[dst[base + i * 256]], 1);
        return;
    }
    __shared__ unsigned short As[32 * 128];   // 8 KB, swizzled
    __shared__ unsigned short Bs[128 * 128];  // 32 KB, swizzled (Bt[n][k])
    const int id = blockIdx.x - HIST_NBLK;
    const int half = id / GEMM_MBLK;
    const int blk = id % GEMM_MBLK;
    const size_t n0 = (size_t)blk * 32;
    const float* __restrict__ W = half ? Wr : Wl;

    // stage A: x[32][128] f32 -> bf16 swizzled
    {
        const int r = t >> 3, s = t & 7;
        const float* xr = x + (n0 + r) * 128 + s * 16;
        float4 f0 = *(const float4*)(xr + 0);
        float4 f1 = *(const float4*)(xr + 4);
        float4 f2 = *(const float4*)(xr + 8);
        float4 f3 = *(const float4*)(xr + 12);
        uint4 p0 = { pk2(f0.x, f0.y), pk2(f0.z, f0.w), pk2(f1.x, f1.y), pk2(f1.z, f1.w) };
        uint4 p1 = { pk2(f2.x, f2.y), pk2(f2.z, f2.w), pk2(f3.x, f3.y), pk2(f3.z, f3.w) };
        int sw = (r & 7) << 3;
        *(uint4*)&As[(r * 128 + s * 16 + 0) ^ sw] = p0;
        *(uint4*)&As[(r * 128 + s * 16 + 8) ^ sw] = p1;
    }
    // stage B: Bt[n][k] = W[k][n] f32 -> bf16 swizzled; thread: col n = t&127, k-half = t>>7
    {
        const int n = t & 127, kh = t >> 7;
        const float* wc = W + n;
        int sw = (n & 7) << 3;
#pragma unroll
        for (int k = kh * 64; k < kh * 64 + 64; k += 8) {
            float a0 = wc[(k + 0) * 128], a1 = wc[(k + 1) * 128];
            float a2 = wc[(k + 2) * 128], a3 = wc[(k + 3) * 128];
            float a4 = wc[(k + 4) * 128], a5 = wc[(k + 5) * 128];
            float a6 = wc[(k + 6) * 128], a7 = wc[(k + 7) * 128];
            uint4 p = { pk2(a0, a1), pk2(a2, a3), pk2(a4, a5), pk2(a6, a7) };
            *(uint4*)&Bs[(n * 128 + k) ^ sw] = p;
        }
    }
    __syncthreads();

    const int w = t >> 6, l = t & 63;
    const int lr = l & 15, lg = l >> 4;
    v4f acc00 = {0.f, 0.f, 0.f, 0.f}, acc01 = acc00, acc10 = acc00, acc11 = acc00;
    const int swA = (lr & 7) << 3;
    const int nA = w * 32 + lr;
    const int swB = (nA & 7) << 3;
#pragma unroll
    for (int ks = 0; ks < 4; ++ks) {
        const int ka = ks * 32 + lg * 8;
        v8s a0 = *(const v8s*)&As[(lr * 128 + ka) ^ swA];
        v8s a1 = *(const v8s*)&As[((16 + lr) * 128 + ka) ^ swA];
        v8s b0 = *(const v8s*)&Bs[(nA * 128 + ka) ^ swB];
        v8s b1 = *(const v8s*)&Bs[((nA + 16) * 128 + ka) ^ swB];
        acc00 = __builtin_amdgcn_mfma_f32_16x16x32_bf16(a0, b0, acc00, 0, 0, 0);
        acc01 = __builtin_amdgcn_mfma_f32_16x16x32_bf16(a0, b1, acc01, 0, 0, 0);
        acc10 = __builtin_amdgcn_mfma_f32_16x16x32_bf16(a1, b0, acc10, 0, 0, 0);
        acc11 = __builtin_amdgcn_mfma_f32_16x16x32_bf16(a1, b1, acc11, 0, 0, 0);
    }
    unsigned short* __restrict__ ob = half ? r1b : t1b;
    const int col0 = w * 32 + lr;
#pragma unroll
    for (int reg = 0; reg < 4; ++reg) {
        size_t row0 = n0 + lg * 4 + reg;
        size_t row1 = row0 + 16;
        ob[row0 * 128 + col0]      = f2bf(acc00[reg]);
        ob[row0 * 128 + col0 + 16] = f2bf(acc01[reg]);
        ob[row1 * 128 + col0]      = f2bf(acc10[reg]);
        ob[row1 * 128 + col0 + 16] = f2bf(acc11[reg]);
    }
}

// ---------- layer 1 aggregate: one row per wave, ushort2 per lane, 8-deep unroll ----------
__global__ __launch_bounds__(256) void k_agg1(const unsigned short* __restrict__ t1b,
                                              const unsigned short* __restrict__ r1b,
                                              const int* __restrict__ rowptr,
                                              const int* __restrict__ ssrc, const float* __restrict__ b1,
                                              float* __restrict__ hpre, float* __restrict__ bn) {
    const int wv = threadIdx.x >> 6;
    const int l  = threadIdx.x & 63;
    const int nbase = blockIdx.x * 32;
    const float bias0 = b1[2 * l], bias1 = b1[2 * l + 1];
    float sa0 = 0.f, sa1 = 0.f, sq0 = 0.f, sq1 = 0.f;

    for (int r = wv; r < 32; r += 4) {
        const int n = nbase + r;
        const int lo = rowptr[n], hi = rowptr[n + 1];
        float a0 = 0.f, a1 = 0.f, b0 = 0.f, b1f = 0.f;
        int i = lo;
        for (; i + 8 <= hi; i += 8) {
            int s0 = ssrc[i], s1 = ssrc[i + 1], s2 = ssrc[i + 2], s3 = ssrc[i + 3];
            int s4 = ssrc[i + 4], s5 = ssrc[i + 5], s6 = ssrc[i + 6], s7 = ssrc[i + 7];
            unsigned int u0 = *(const unsigned int*)&t1b[(size_t)s0 * 128 + 2 * l];
            unsigned int u1 = *(const unsigned int*)&t1b[(size_t)s1 * 128 + 2 * l];
            unsigned int u2 = *(const unsigned int*)&t1b[(size_t)s2 * 128 + 2 * l];
            unsigned int u3 = *(const unsigned int*)&t1b[(size_t)s3 * 128 + 2 * l];
            unsigned int u4 = *(const unsigned int*)&t1b[(size_t)s4 * 128 + 2 * l];
            unsigned int u5 = *(const unsigned int*)&t1b[(size_t)s5 * 128 + 2 * l];
            unsigned int u6 = *(const unsigned int*)&t1b[(size_t)s6 * 128 + 2 * l];
            unsigned int u7 = *(const unsigned int*)&t1b[(size_t)s7 * 128 + 2 * l];
            a0 += bf2f_lo(u0) + bf2f_lo(u1); a1 += bf2f_hi(u0) + bf2f_hi(u1);
            b0 += bf2f_lo(u2) + bf2f_lo(u3); b1f += bf2f_hi(u2) + bf2f_hi(u3);
            a0 += bf2f_lo(u4) + bf2f_lo(u5); a1 += bf2f_hi(u4) + bf2f_hi(u5);
            b0 += bf2f_lo(u6) + bf2f_lo(u7); b1f += bf2f_hi(u6) + bf2f_hi(u7);
        }
        for (; i < hi; ++i) {
            unsigned int u = *(const unsigned int*)&t1b[(size_t)ssrc[i] * 128 + 2 * l];
            a0 += bf2f_lo(u); a1 += bf2f_hi(u);
        }
        float c = (float)(hi - lo);
        if (c < 1.f) c = 1.f;
        float inv = 1.0f / c;
        unsigned int ur = *(const unsigned int*)&r1b[(size_t)n * 128 + 2 * l];
        float v0 = (a0 + b0) * inv + bias0 + bf2f_lo(ur);
        float v1 = (a1 + b1f) * inv + bias1 + bf2f_hi(ur);
        *(float2*)&hpre[(size_t)n * 128 + 2 * l] = make_float2(v0, v1);
        sa0 += v0; sa1 += v1; sq0 += v0 * v0; sq1 += v1 * v1;
    }

    __shared__ float red[2][4][128];
    red[0][wv][2 * l] = sa0; red[0][wv][2 * l + 1] = sa1;
    red[1][wv][2 * l] = sq0; red[1][wv][2 * l + 1] = sq1;
    __syncthreads();
    int t = threadIdx.x;
    if (t < 128) {
        atomicAdd(&bn[t], red[0][0][t] + red[0][1][t] + red[0][2][t] + red[0][3][t]);
    } else {
        int f = t - 128;
        atomicAdd(&bn[128 + f], red[1][0][f] + red[1][1][f] + red[1][2][f] + red[1][3][f]);
    }
}

// ---------- BN finalize ----------
__global__ void k_bnfin(float* __restrict__ bn, const float* __restrict__ gamma, const float* __restrict__ beta) {
    int f = threadIdx.x;  // 128
    float mean = bn[f] * (1.0f / N_NODES);
    float var = bn[128 + f] * (1.0f / N_NODES) - mean * mean;
    float sc = gamma[f] * rsqrtf(var + EPSV);
    bn[f] = sc;
    bn[128 + f] = beta[f] - mean * sc;
}

// ---------- layer 2 MFMA GEMM with fused BN+ReLU: [t2b|r2b] = bf16(relu(bn(hpre)) @ [Wl2|Wr2]) ----------
__global__ __launch_bounds__(256) void k_gemm2m(const float* __restrict__ hpre, const float* __restrict__ bnp,
                                                const float* __restrict__ Wl, const float* __restrict__ Wr,
                                                unsigned short* __restrict__ t2b,
                                                unsigned short* __restrict__ r2b) {
    __shared__ unsigned short As[32 * 128];   // 8 KB
    __shared__ unsigned short Bs[128 * 128];  // 32 KB
    const int t = threadIdx.x;
    const size_t n0 = (size_t)blockIdx.x * 32;

    // stage A: relu(bn(hpre[32][128])) -> bf16 swizzled
    {
        const int r = t >> 3, s = t & 7;
        const float* hr = hpre + (n0 + r) * 128 + s * 16;
        float v[16];
        *(float4*)&v[0]  = *(const float4*)(hr + 0);
        *(float4*)&v[4]  = *(const float4*)(hr + 4);
        *(float4*)&v[8]  = *(const float4*)(hr + 8);
        *(float4*)&v[12] = *(const float4*)(hr + 12);
#pragma unroll
        for (int j = 0; j < 16; ++j) {
            int f = s * 16 + j;
            float val = fmaf(bnp[f], v[j], bnp[128 + f]);
            v[j] = val > 0.f ? val : 0.f;
        }
        uint4 p0 = { pk2(v[0], v[1]), pk2(v[2], v[3]), pk2(v[4], v[5]), pk2(v[6], v[7]) };
        uint4 p1 = { pk2(v[8], v[9]), pk2(v[10], v[11]), pk2(v[12], v[13]), pk2(v[14], v[15]) };
        int sw = (r & 7) << 3;
        *(uint4*)&As[(r * 128 + s * 16 + 0) ^ sw] = p0;
        *(uint4*)&As[(r * 128 + s * 16 + 8) ^ sw] = p1;
    }
    // stage B: Bt[n][k]; n<64 -> Wl2[k][n], n>=64 -> Wr2[k][n-64] (both [128][64] row-major)
    {
        const int n = t & 127, kh = t >> 7;
        const float* wc = (n < 64) ? (Wl + n) : (Wr + (n - 64));
        int sw = (n & 7) << 3;
#pragma unroll
        for (int k = kh * 64; k < kh * 64 + 64; k += 8) {
            float a0 = wc[(k + 0) * 64], a1 = wc[(k + 1) * 64];
            float a2 = wc[(k + 2) * 64], a3 = wc[(k + 3) * 64];
            float a4 = wc[(k + 4) * 64], a5 = wc[(k + 5) * 64];
            float a6 = wc[(k + 6) * 64], a7 = wc[(k + 7) * 64];
            uint4 p = { pk2(a0, a1), pk2(a2, a3), pk2(a4, a5), pk2(a6, a7) };
            *(uint4*)&Bs[(n * 128 + k) ^ sw] = p;
        }
    }
    __syncthreads();

    const int w = t >> 6, l = t & 63;
    const int lr = l & 15, lg = l >> 4;
    v4f acc00 = {0.f, 0.f, 0.f, 0.f}, acc01 = acc00, acc10 = acc00, acc11 = acc00;
    const int swA = (lr & 7) << 3;
    const int nA = w * 32 + lr;
    const int swB = (nA & 7) << 3;
#pragma unroll
    for (int ks = 0; ks < 4; ++ks) {
        const int ka = ks * 32 + lg * 8;
        v8s a0 = *(const v8s*)&As[(lr * 128 + ka) ^ swA];
        v8s a1 = *(const v8s*)&As[((16 + lr) * 128 + ka) ^ swA];
        v8s b0 = *(const v8s*)&Bs[(nA * 128 + ka) ^ swB];
        v8s b1 = *(const v8s*)&Bs[((nA + 16) * 128 + ka) ^ swB];
        acc00 = __builtin_amdgcn_mfma_f32_16x16x32_bf16(a0, b0, acc00, 0, 0, 0);
        acc01 = __builtin_amdgcn_mfma_f32_16x16x32_bf16(a0, b1, acc01, 0, 0, 0);
        acc10 = __builtin_amdgcn_mfma_f32_16x16x32_bf16(a1, b0, acc10, 0, 0, 0);
        acc11 = __builtin_amdgcn_mfma_f32_16x16x32_bf16(a1, b1, acc11, 0, 0, 0);
    }
    unsigned short* __restrict__ ob = (w < 2) ? t2b : r2b;
    const int col0 = (w < 2) ? (w * 32 + lr) : ((w - 2) * 32 + lr);
#pragma unroll
    for (int reg = 0; reg < 4; ++reg) {
        size_t row0 = n0 + lg * 4 + reg;
        size_t row1 = row0 + 16;
        ob[row0 * 64 + col0]      = f2bf(acc00[reg]);
        ob[row0 * 64 + col0 + 16] = f2bf(acc01[reg]);
        ob[row1 * 64 + col0]      = f2bf(acc10[reg]);
        ob[row1 * 64 + col0 + 16] = f2bf(acc11[reg]);
    }
}

// ---------- layer 2 aggregate ----------
__global__ __launch_bounds__(256) void k_agg2(const unsigned short* __restrict__ t2b,
                                              const unsigned short* __restrict__ r2b,
                                              const int* __restrict__ rowptr,
                                              const int* __restrict__ ssrc, const float* __restrict__ b2,
                                              float* __restrict__ out) {
    const int wv = threadIdx.x >> 6;
    const int l  = threadIdx.x & 63;
    const int nbase = blockIdx.x * 16;
    const float bias = b2[l];

    for (int r = wv; r < 16; r += 4) {
        const int n = nbase + r;
        const int lo = rowptr[n], hi = rowptr[n + 1];
        float a0 = 0.f, a1 = 0.f;
        int i = lo;
        for (; i + 8 <= hi; i += 8) {
            int s0 = ssrc[i], s1 = ssrc[i + 1], s2 = ssrc[i + 2], s3 = ssrc[i + 3];
            int s4 = ssrc[i + 4], s5 = ssrc[i + 5], s6 = ssrc[i + 6], s7 = ssrc[i + 7];
            float f0 = bf2f(t2b[(size_t)s0 * 64 + l]);
            float f1 = bf2f(t2b[(size_t)s1 * 64 + l]);
            float f2 = bf2f(t2b[(size_t)s2 * 64 + l]);
            float f3 = bf2f(t2b[(size_t)s3 * 64 + l]);
            float f4 = bf2f(t2b[(size_t)s4 * 64 + l]);
            float f5 = bf2f(t2b[(size_t)s5 * 64 + l]);
            float f6 = bf2f(t2b[(size_t)s6 * 64 + l]);
            float f7 = bf2f(t2b[(size_t)s7 * 64 + l]);
            a0 += (f0 + f1) + (f2 + f3);
            a1 += (f4 + f5) + (f6 + f7);
        }
        for (; i < hi; ++i) a0 += bf2f(t2b[(size_t)ssrc[i] * 64 + l]);
        float c = (float)(hi - lo);
        if (c < 1.f) c = 1.f;
        out[(size_t)n * 64 + l] = (a0 + a1) / c + bias + bf2f(r2b[(size_t)n * 64 + l]);
    }
}

extern "C" void kernel_launch(void* const* d_in, const int* in_sizes, int n_in,
                              void* d_out, int out_size, void* d_ws, size_t ws_size,
                              hipStream_t stream) {
    const float* x      = (const float*)d_in[0];
    const int*   ei     = (const int*)d_in[1];
    const float* Wl1    = (const float*)d_in[2];
    const float* b1     = (const float*)d_in[3];
    const float* Wr1    = (const float*)d_in[4];
    const float* gamma1 = (const float*)d_in[5];
    const float* beta1  = (const float*)d_in[6];
    const float* Wl2    = (const float*)d_in[7];
    const float* b2     = (const float*)d_in[8];
    const float* Wr2    = (const float*)d_in[9];
    float* out = (float*)d_out;

    char* ws = (char*)d_ws;
    int*            rowptr = (int*)(ws + OFF_ROWPTR);
    int*            deg    = (int*)(ws + OFF_DEG);
    float*          bn     = (float*)(ws + OFF_BN);
    int*            ssrc   = (int*)(ws + OFF_SRC);
    unsigned short* t1b    = (unsigned short*)(ws + OFF_T1B);
    unsigned short* r1b    = (unsigned short*)(ws + OFF_R1B);
    float*          hpre   = (float*)(ws + OFF_HPRE);
    unsigned short* t2b    = t1b;                 // reuse: dead after k_agg1
    unsigned short* r2b    = r1b;                 // reuse: dead after k_agg1
    int*            bsums  = (int*)(ws + OFF_HPRE);  // hpre not written until k_agg1 (after scans)

    const int* esrc = ei;
    const int* edst = ei + N_EDGES;

    hipMemsetAsync(deg, 0, N_NODES * sizeof(int), stream);
    hipMemsetAsync(bn, 0, 256 * sizeof(float), stream);

    k_gemm1h<<<HIST_NBLK + 2 * GEMM_MBLK, 256, 0, stream>>>(x, Wl1, Wr1, t1b, r1b, edst, deg);
    k_scan_a<<<SCAN_NBLK, 1024, 0, stream>>>(deg, rowptr, bsums);
    k_scan_b<<<1, 128, 0, stream>>>(bsums);
    k_scan_c<<<SCAN_NBLK, 1024, 0, stream>>>(rowptr, deg, bsums);
    k_scatter<<<N_EDGES / 256, 256, 0, stream>>>(esrc, edst, deg, ssrc);

    k_agg1<<<N_NODES / 32, 256, 0, stream>>>(t1b, r1b, rowptr, ssrc, b1, hpre, bn);
    k_bnfin<<<1, 128, 0, stream>>>(bn, gamma1, beta1);
    k_gemm2m<<<GEMM_MBLK, 256, 0, stream>>>(hpre, bn, Wl2, Wr2, t2b, r2b);
    k_agg2<<<N_NODES / 16, 256, 0, stream>>>(t2b, r2b, rowptr, ssrc, b2, out);
}

// Round 7
// 429.542 us; speedup vs baseline: 1.9152x; 1.0377x over previous
//
#include <hip/hip_runtime.h>
#include <hip/hip_bf16.h>
#include <cstdint>
#include <cstddef>

#define N_NODES 100000
#define N_EDGES 1600000
#define EPSV 1e-5f

// ---- workspace layout (bytes) ----
// rowptr @0 | deg @400384 | bn @800768 | ssrc @801792
// t1b: N*128 fp8 (12.8MB) @7201792   -> later t2b (N*64 bf16, 12.8MB)
// r1b: N*128 bf16 (25.6MB) @32801792 -> later r2b (N*64 bf16)
// hpre: N*128 bf16 (25.6MB) @58401792 ; bsums overlaps hpre (dead before k_agg1)
#define OFF_ROWPTR 0
#define OFF_DEG    400384
#define OFF_BN     800768
#define OFF_SRC    801792
#define OFF_T1B    7201792
#define OFF_R1B    32801792
#define OFF_HPRE   58401792

#define SCAN_NBLK 98      // ceil(100000/1024)
#define GEMM_MBLK 3125    // 100000/32 row-tiles
#define HIST_NBLK 625     // 625*256*10 = 1.6M edges

typedef short v8s __attribute__((ext_vector_type(8)));
typedef float v4f __attribute__((ext_vector_type(4)));
typedef float v2f __attribute__((ext_vector_type(2)));

__device__ __forceinline__ float bf2f(unsigned short u) {
    return __uint_as_float(((unsigned int)u) << 16);
}
__device__ __forceinline__ float bf2f_lo(unsigned int u) {
    return __uint_as_float(u << 16);
}
__device__ __forceinline__ float bf2f_hi(unsigned int u) {
    return __uint_as_float(u & 0xffff0000u);
}
__device__ __forceinline__ unsigned short f2bf(float f) {
    unsigned int u = __float_as_uint(f);
    u += 0x7fffu + ((u >> 16) & 1u);   // round-to-nearest-even
    return (unsigned short)(u >> 16);
}
__device__ __forceinline__ unsigned int pk2(float a, float b) {
    return (unsigned int)f2bf(a) | ((unsigned int)f2bf(b) << 16);
}
__device__ __forceinline__ unsigned char f2fp8(float v) {
    return (unsigned char)(__builtin_amdgcn_cvt_pk_fp8_f32(v, v, 0, 0) & 0xff);
}

// ---------- CSR scan ----------
__global__ __launch_bounds__(1024) void k_scan_a(const int* __restrict__ deg, int* __restrict__ rowptr,
                                                 int* __restrict__ bsums) {
    __shared__ int s[1024];
    const int t = threadIdx.x;
    const int i = blockIdx.x * 1024 + t;
    int v = (i < N_NODES) ? deg[i] : 0;
    s[t] = v;
    __syncthreads();
    for (int off = 1; off < 1024; off <<= 1) {
        int u = (t >= off) ? s[t - off] : 0;
        __syncthreads();
        s[t] += u;
        __syncthreads();
    }
    if (i < N_NODES) rowptr[i] = s[t] - v;
    if (t == 1023) bsums[blockIdx.x] = s[1023];
}

__global__ __launch_bounds__(128) void k_scan_b(int* __restrict__ bsums) {
    __shared__ int s[128];
    const int t = threadIdx.x;
    int v = (t < SCAN_NBLK) ? bsums[t] : 0;
    s[t] = v;
    __syncthreads();
    for (int off = 1; off < 128; off <<= 1) {
        int u = (t >= off) ? s[t - off] : 0;
        __syncthreads();
        s[t] += u;
        __syncthreads();
    }
    if (t < SCAN_NBLK) bsums[t] = s[t] - v;
}

__global__ __launch_bounds__(1024) void k_scan_c(int* __restrict__ rowptr, int* __restrict__ cursor,
                                                 const int* __restrict__ bsums) {
    const int i = blockIdx.x * 1024 + threadIdx.x;
    if (i < N_NODES) {
        int r = rowptr[i] + bsums[blockIdx.x];
        rowptr[i] = r;
        cursor[i] = r;
    }
    if (i == N_NODES) rowptr[N_NODES] = N_EDGES;
}

__global__ __launch_bounds__(256) void k_scatter(const int* __restrict__ src, const int* __restrict__ dst,
                                                 int* __restrict__ cursor, int* __restrict__ ssrc) {
    int e = blockIdx.x * 256 + threadIdx.x;
    int d = dst[e];
    int pos = atomicAdd(&cursor[d], 1);
    ssrc[pos] = src[e];
}

// ---------- fused: degree histogram (blocks 0..624) + layer-1 MFMA GEMM ----------
// half 0 -> t1b (fp8, gathered later), half 1 -> r1b (bf16, streamed later)
__global__ __launch_bounds__(256) void k_gemm1h(const float* __restrict__ x, const float* __restrict__ Wl,
                                                const float* __restrict__ Wr,
                                                unsigned char* __restrict__ t1b8,
                                                unsigned short* __restrict__ r1b,
                                                const int* __restrict__ dst, int* __restrict__ deg) {
    const int t = threadIdx.x;
    if (blockIdx.x < HIST_NBLK) {
        int base = blockIdx.x * 2560 + t;
#pragma unroll
        for (int i = 0; i < 10; ++i) atomicAdd(&deg[dst[base + i * 256]], 1);
        return;
    }
    __shared__ unsigned short As[32 * 128];   // 8 KB, swizzled
    __shared__ unsigned short Bs[128 * 128];  // 32 KB, swizzled (Bt[n][k])
    const int id = blockIdx.x - HIST_NBLK;
    const int half = id / GEMM_MBLK;
    const int blk = id % GEMM_MBLK;
    const size_t n0 = (size_t)blk * 32;
    const float* __restrict__ W = half ? Wr : Wl;

    // stage A: x[32][128] f32 -> bf16 swizzled
    {
        const int r = t >> 3, s = t & 7;
        const float* xr = x + (n0 + r) * 128 + s * 16;
        float4 f0 = *(const float4*)(xr + 0);
        float4 f1 = *(const float4*)(xr + 4);
        float4 f2 = *(const float4*)(xr + 8);
        float4 f3 = *(const float4*)(xr + 12);
        uint4 p0 = { pk2(f0.x, f0.y), pk2(f0.z, f0.w), pk2(f1.x, f1.y), pk2(f1.z, f1.w) };
        uint4 p1 = { pk2(f2.x, f2.y), pk2(f2.z, f2.w), pk2(f3.x, f3.y), pk2(f3.z, f3.w) };
        int sw = (r & 7) << 3;
        *(uint4*)&As[(r * 128 + s * 16 + 0) ^ sw] = p0;
        *(uint4*)&As[(r * 128 + s * 16 + 8) ^ sw] = p1;
    }
    // stage B: Bt[n][k] = W[k][n] f32 -> bf16 swizzled
    {
        const int n = t & 127, kh = t >> 7;
        const float* wc = W + n;
        int sw = (n & 7) << 3;
#pragma unroll
        for (int k = kh * 64; k < kh * 64 + 64; k += 8) {
            float a0 = wc[(k + 0) * 128], a1 = wc[(k + 1) * 128];
            float a2 = wc[(k + 2) * 128], a3 = wc[(k + 3) * 128];
            float a4 = wc[(k + 4) * 128], a5 = wc[(k + 5) * 128];
            float a6 = wc[(k + 6) * 128], a7 = wc[(k + 7) * 128];
            uint4 p = { pk2(a0, a1), pk2(a2, a3), pk2(a4, a5), pk2(a6, a7) };
            *(uint4*)&Bs[(n * 128 + k) ^ sw] = p;
        }
    }
    __syncthreads();

    const int w = t >> 6, l = t & 63;
    const int lr = l & 15, lg = l >> 4;
    v4f acc00 = {0.f, 0.f, 0.f, 0.f}, acc01 = acc00, acc10 = acc00, acc11 = acc00;
    const int swA = (lr & 7) << 3;
    const int nA = w * 32 + lr;
    const int swB = (nA & 7) << 3;
#pragma unroll
    for (int ks = 0; ks < 4; ++ks) {
        const int ka = ks * 32 + lg * 8;
        v8s a0 = *(const v8s*)&As[(lr * 128 + ka) ^ swA];
        v8s a1 = *(const v8s*)&As[((16 + lr) * 128 + ka) ^ swA];
        v8s b0 = *(const v8s*)&Bs[(nA * 128 + ka) ^ swB];
        v8s b1 = *(const v8s*)&Bs[((nA + 16) * 128 + ka) ^ swB];
        acc00 = __builtin_amdgcn_mfma_f32_16x16x32_bf16(a0, b0, acc00, 0, 0, 0);
        acc01 = __builtin_amdgcn_mfma_f32_16x16x32_bf16(a0, b1, acc01, 0, 0, 0);
        acc10 = __builtin_amdgcn_mfma_f32_16x16x32_bf16(a1, b0, acc10, 0, 0, 0);
        acc11 = __builtin_amdgcn_mfma_f32_16x16x32_bf16(a1, b1, acc11, 0, 0, 0);
    }
    const int col0 = w * 32 + lr;
    if (half == 0) {
#pragma unroll
        for (int reg = 0; reg < 4; ++reg) {
            size_t row0 = n0 + lg * 4 + reg;
            size_t row1 = row0 + 16;
            t1b8[row0 * 128 + col0]      = f2fp8(acc00[reg]);
            t1b8[row0 * 128 + col0 + 16] = f2fp8(acc01[reg]);
            t1b8[row1 * 128 + col0]      = f2fp8(acc10[reg]);
            t1b8[row1 * 128 + col0 + 16] = f2fp8(acc11[reg]);
        }
    } else {
#pragma unroll
        for (int reg = 0; reg < 4; ++reg) {
            size_t row0 = n0 + lg * 4 + reg;
            size_t row1 = row0 + 16;
            r1b[row0 * 128 + col0]      = f2bf(acc00[reg]);
            r1b[row0 * 128 + col0 + 16] = f2bf(acc01[reg]);
            r1b[row1 * 128 + col0]      = f2bf(acc10[reg]);
            r1b[row1 * 128 + col0 + 16] = f2bf(acc11[reg]);
        }
    }
}

// ---------- layer 1 aggregate: one row per wave, fp8 ushort (2 features) per lane ----------
__global__ __launch_bounds__(256) void k_agg1(const unsigned char* __restrict__ t1b8,
                                              const unsigned short* __restrict__ r1b,
                                              const int* __restrict__ rowptr,
                                              const int* __restrict__ ssrc, const float* __restrict__ b1,
                                              unsigned short* __restrict__ hpreb, float* __restrict__ bn) {
    const int wv = threadIdx.x >> 6;
    const int l  = threadIdx.x & 63;
    const int nbase = blockIdx.x * 32;
    const float bias0 = b1[2 * l], bias1 = b1[2 * l + 1];
    float sa0 = 0.f, sa1 = 0.f, sq0 = 0.f, sq1 = 0.f;

    for (int r = wv; r < 32; r += 4) {
        const int n = nbase + r;
        const int lo = rowptr[n], hi = rowptr[n + 1];
        float a0 = 0.f, a1 = 0.f, b0 = 0.f, b1f = 0.f;
        int i = lo;
        for (; i + 8 <= hi; i += 8) {
            int s0 = ssrc[i], s1 = ssrc[i + 1], s2 = ssrc[i + 2], s3 = ssrc[i + 3];
            int s4 = ssrc[i + 4], s5 = ssrc[i + 5], s6 = ssrc[i + 6], s7 = ssrc[i + 7];
            unsigned short u0 = *(const unsigned short*)&t1b8[(size_t)s0 * 128 + 2 * l];
            unsigned short u1 = *(const unsigned short*)&t1b8[(size_t)s1 * 128 + 2 * l];
            unsigned short u2 = *(const unsigned short*)&t1b8[(size_t)s2 * 128 + 2 * l];
            unsigned short u3 = *(const unsigned short*)&t1b8[(size_t)s3 * 128 + 2 * l];
            unsigned short u4 = *(const unsigned short*)&t1b8[(size_t)s4 * 128 + 2 * l];
            unsigned short u5 = *(const unsigned short*)&t1b8[(size_t)s5 * 128 + 2 * l];
            unsigned short u6 = *(const unsigned short*)&t1b8[(size_t)s6 * 128 + 2 * l];
            unsigned short u7 = *(const unsigned short*)&t1b8[(size_t)s7 * 128 + 2 * l];
            v2f f0 = __builtin_amdgcn_cvt_pk_f32_fp8((int)u0, 0);
            v2f f1 = __builtin_amdgcn_cvt_pk_f32_fp8((int)u1, 0);
            v2f f2 = __builtin_amdgcn_cvt_pk_f32_fp8((int)u2, 0);
            v2f f3 = __builtin_amdgcn_cvt_pk_f32_fp8((int)u3, 0);
            v2f f4 = __builtin_amdgcn_cvt_pk_f32_fp8((int)u4, 0);
            v2f f5 = __builtin_amdgcn_cvt_pk_f32_fp8((int)u5, 0);
            v2f f6 = __builtin_amdgcn_cvt_pk_f32_fp8((int)u6, 0);
            v2f f7 = __builtin_amdgcn_cvt_pk_f32_fp8((int)u7, 0);
            a0 += f0[0] + f1[0]; a1 += f0[1] + f1[1];
            b0 += f2[0] + f3[0]; b1f += f2[1] + f3[1];
            a0 += f4[0] + f5[0]; a1 += f4[1] + f5[1];
            b0 += f6[0] + f7[0]; b1f += f6[1] + f7[1];
        }
        for (; i < hi; ++i) {
            unsigned short u = *(const unsigned short*)&t1b8[(size_t)ssrc[i] * 128 + 2 * l];
            v2f f = __builtin_amdgcn_cvt_pk_f32_fp8((int)u, 0);
            a0 += f[0]; a1 += f[1];
        }
        float c = (float)(hi - lo);
        if (c < 1.f) c = 1.f;
        float inv = 1.0f / c;
        unsigned int ur = *(const unsigned int*)&r1b[(size_t)n * 128 + 2 * l];
        float v0 = (a0 + b0) * inv + bias0 + bf2f_lo(ur);
        float v1 = (a1 + b1f) * inv + bias1 + bf2f_hi(ur);
        *(unsigned int*)&hpreb[(size_t)n * 128 + 2 * l] = pk2(v0, v1);
        sa0 += v0; sa1 += v1; sq0 += v0 * v0; sq1 += v1 * v1;
    }

    __shared__ float red[2][4][128];
    red[0][wv][2 * l] = sa0; red[0][wv][2 * l + 1] = sa1;
    red[1][wv][2 * l] = sq0; red[1][wv][2 * l + 1] = sq1;
    __syncthreads();
    int t = threadIdx.x;
    if (t < 128) {
        atomicAdd(&bn[t], red[0][0][t] + red[0][1][t] + red[0][2][t] + red[0][3][t]);
    } else {
        int f = t - 128;
        atomicAdd(&bn[128 + f], red[1][0][f] + red[1][1][f] + red[1][2][f] + red[1][3][f]);
    }
}

// ---------- BN finalize ----------
__global__ void k_bnfin(float* __restrict__ bn, const float* __restrict__ gamma, const float* __restrict__ beta) {
    int f = threadIdx.x;  // 128
    float mean = bn[f] * (1.0f / N_NODES);
    float var = bn[128 + f] * (1.0f / N_NODES) - mean * mean;
    float sc = gamma[f] * rsqrtf(var + EPSV);
    bn[f] = sc;
    bn[128 + f] = beta[f] - mean * sc;
}

// ---------- layer 2 MFMA GEMM with fused BN+ReLU ----------
__global__ __launch_bounds__(256) void k_gemm2m(const unsigned short* __restrict__ hpreb,
                                                const float* __restrict__ bnp,
                                                const float* __restrict__ Wl, const float* __restrict__ Wr,
                                                unsigned short* __restrict__ t2b,
                                                unsigned short* __restrict__ r2b) {
    __shared__ unsigned short As[32 * 128];   // 8 KB
    __shared__ unsigned short Bs[128 * 128];  // 32 KB
    const int t = threadIdx.x;
    const size_t n0 = (size_t)blockIdx.x * 32;

    // stage A: relu(bn(hpre[32][128] bf16)) -> bf16 swizzled
    {
        const int r = t >> 3, s = t & 7;
        const unsigned short* hr = hpreb + (n0 + r) * 128 + s * 16;
        uint4 h0 = *(const uint4*)(hr + 0);
        uint4 h1 = *(const uint4*)(hr + 8);
        unsigned int hv[8] = { h0.x, h0.y, h0.z, h0.w, h1.x, h1.y, h1.z, h1.w };
        float v[16];
#pragma unroll
        for (int j = 0; j < 8; ++j) {
            v[2 * j]     = bf2f_lo(hv[j]);
            v[2 * j + 1] = bf2f_hi(hv[j]);
        }
#pragma unroll
        for (int j = 0; j < 16; ++j) {
            int f = s * 16 + j;
            float val = fmaf(bnp[f], v[j], bnp[128 + f]);
            v[j] = val > 0.f ? val : 0.f;
        }
        uint4 p0 = { pk2(v[0], v[1]), pk2(v[2], v[3]), pk2(v[4], v[5]), pk2(v[6], v[7]) };
        uint4 p1 = { pk2(v[8], v[9]), pk2(v[10], v[11]), pk2(v[12], v[13]), pk2(v[14], v[15]) };
        int sw = (r & 7) << 3;
        *(uint4*)&As[(r * 128 + s * 16 + 0) ^ sw] = p0;
        *(uint4*)&As[(r * 128 + s * 16 + 8) ^ sw] = p1;
    }
    // stage B
    {
        const int n = t & 127, kh = t >> 7;
        const float* wc = (n < 64) ? (Wl + n) : (Wr + (n - 64));
        int sw = (n & 7) << 3;
#pragma unroll
        for (int k = kh * 64; k < kh * 64 + 64; k += 8) {
            float a0 = wc[(k + 0) * 64], a1 = wc[(k + 1) * 64];
            float a2 = wc[(k + 2) * 64], a3 = wc[(k + 3) * 64];
            float a4 = wc[(k + 4) * 64], a5 = wc[(k + 5) * 64];
            float a6 = wc[(k + 6) * 64], a7 = wc[(k + 7) * 64];
            uint4 p = { pk2(a0, a1), pk2(a2, a3), pk2(a4, a5), pk2(a6, a7) };
            *(uint4*)&Bs[(n * 128 + k) ^ sw] = p;
        }
    }
    __syncthreads();

    const int w = t >> 6, l = t & 63;
    const int lr = l & 15, lg = l >> 4;
    v4f acc00 = {0.f, 0.f, 0.f, 0.f}, acc01 = acc00, acc10 = acc00, acc11 = acc00;
    const int swA = (lr & 7) << 3;
    const int nA = w * 32 + lr;
    const int swB = (nA & 7) << 3;
#pragma unroll
    for (int ks = 0; ks < 4; ++ks) {
        const int ka = ks * 32 + lg * 8;
        v8s a0 = *(const v8s*)&As[(lr * 128 + ka) ^ swA];
        v8s a1 = *(const v8s*)&As[((16 + lr) * 128 + ka) ^ swA];
        v8s b0 = *(const v8s*)&Bs[(nA * 128 + ka) ^ swB];
        v8s b1 = *(const v8s*)&Bs[((nA + 16) * 128 + ka) ^ swB];
        acc00 = __builtin_amdgcn_mfma_f32_16x16x32_bf16(a0, b0, acc00, 0, 0, 0);
        acc01 = __builtin_amdgcn_mfma_f32_16x16x32_bf16(a0, b1, acc01, 0, 0, 0);
        acc10 = __builtin_amdgcn_mfma_f32_16x16x32_bf16(a1, b0, acc10, 0, 0, 0);
        acc11 = __builtin_amdgcn_mfma_f32_16x16x32_bf16(a1, b1, acc11, 0, 0, 0);
    }
    unsigned short* __restrict__ ob = (w < 2) ? t2b : r2b;
    const int col0 = (w < 2) ? (w * 32 + lr) : ((w - 2) * 32 + lr);
#pragma unroll
    for (int reg = 0; reg < 4; ++reg) {
        size_t row0 = n0 + lg * 4 + reg;
        size_t row1 = row0 + 16;
        ob[row0 * 64 + col0]      = f2bf(acc00[reg]);
        ob[row0 * 64 + col0 + 16] = f2bf(acc01[reg]);
        ob[row1 * 64 + col0]      = f2bf(acc10[reg]);
        ob[row1 * 64 + col0 + 16] = f2bf(acc11[reg]);
    }
}

// ---------- layer 2 aggregate ----------
__global__ __launch_bounds__(256) void k_agg2(const unsigned short* __restrict__ t2b,
                                              const unsigned short* __restrict__ r2b,
                                              const int* __restrict__ rowptr,
                                              const int* __restrict__ ssrc, const float* __restrict__ b2,
                                              float* __restrict__ out) {
    const int wv = threadIdx.x >> 6;
    const int l  = threadIdx.x & 63;
    const int nbase = blockIdx.x * 16;
    const float bias = b2[l];

    for (int r = wv; r < 16; r += 4) {
        const int n = nbase + r;
        const int lo = rowptr[n], hi = rowptr[n + 1];
        float a0 = 0.f, a1 = 0.f;
        int i = lo;
        for (; i + 8 <= hi; i += 8) {
            int s0 = ssrc[i], s1 = ssrc[i + 1], s2 = ssrc[i + 2], s3 = ssrc[i + 3];
            int s4 = ssrc[i + 4], s5 = ssrc[i + 5], s6 = ssrc[i + 6], s7 = ssrc[i + 7];
            float f0 = bf2f(t2b[(size_t)s0 * 64 + l]);
            float f1 = bf2f(t2b[(size_t)s1 * 64 + l]);
            float f2 = bf2f(t2b[(size_t)s2 * 64 + l]);
            float f3 = bf2f(t2b[(size_t)s3 * 64 + l]);
            float f4 = bf2f(t2b[(size_t)s4 * 64 + l]);
            float f5 = bf2f(t2b[(size_t)s5 * 64 + l]);
            float f6 = bf2f(t2b[(size_t)s6 * 64 + l]);
            float f7 = bf2f(t2b[(size_t)s7 * 64 + l]);
            a0 += (f0 + f1) + (f2 + f3);
            a1 += (f4 + f5) + (f6 + f7);
        }
        for (; i < hi; ++i) a0 += bf2f(t2b[(size_t)ssrc[i] * 64 + l]);
        float c = (float)(hi - lo);
        if (c < 1.f) c = 1.f;
        out[(size_t)n * 64 + l] = (a0 + a1) / c + bias + bf2f(r2b[(size_t)n * 64 + l]);
    }
}

extern "C" void kernel_launch(void* const* d_in, const int* in_sizes, int n_in,
                              void* d_out, int out_size, void* d_ws, size_t ws_size,
                              hipStream_t stream) {
    const float* x      = (const float*)d_in[0];
    const int*   ei     = (const int*)d_in[1];
    const float* Wl1    = (const float*)d_in[2];
    const float* b1     = (const float*)d_in[3];
    const float* Wr1    = (const float*)d_in[4];
    const float* gamma1 = (const float*)d_in[5];
    const float* beta1  = (const float*)d_in[6];
    const float* Wl2    = (const float*)d_in[7];
    const float* b2     = (const float*)d_in[8];
    const float* Wr2    = (const float*)d_in[9];
    float* out = (float*)d_out;

    char* ws = (char*)d_ws;
    int*            rowptr = (int*)(ws + OFF_ROWPTR);
    int*            deg    = (int*)(ws + OFF_DEG);
    float*          bn     = (float*)(ws + OFF_BN);
    int*            ssrc   = (int*)(ws + OFF_SRC);
    unsigned char*  t1b8   = (unsigned char*)(ws + OFF_T1B);
    unsigned short* r1b    = (unsigned short*)(ws + OFF_R1B);
    unsigned short* hpreb  = (unsigned short*)(ws + OFF_HPRE);
    unsigned short* t2b    = (unsigned short*)(ws + OFF_T1B);  // reuse after k_agg1
    unsigned short* r2b    = r1b;                              // reuse after k_agg1
    int*            bsums  = (int*)(ws + OFF_HPRE);            // dead before k_agg1

    const int* esrc = ei;
    const int* edst = ei + N_EDGES;

    hipMemsetAsync(deg, 0, N_NODES * sizeof(int), stream);
    hipMemsetAsync(bn, 0, 256 * sizeof(float), stream);

    k_gemm1h<<<HIST_NBLK + 2 * GEMM_MBLK, 256, 0, stream>>>(x, Wl1, Wr1, t1b8, r1b, edst, deg);
    k_scan_a<<<SCAN_NBLK, 1024, 0, stream>>>(deg, rowptr, bsums);
    k_scan_b<<<1, 128, 0, stream>>>(bsums);
    k_scan_c<<<SCAN_NBLK, 1024, 0, stream>>>(rowptr, deg, bsums);
    k_scatter<<<N_EDGES / 256, 256, 0, stream>>>(esrc, edst, deg, ssrc);

    k_agg1<<<N_NODES / 32, 256, 0, stream>>>(t1b8, r1b, rowptr, ssrc, b1, hpreb, bn);
    k_bnfin<<<1, 128, 0, stream>>>(bn, gamma1, beta1);
    k_gemm2m<<<GEMM_MBLK, 256, 0, stream>>>(hpreb, bn, Wl2, Wr2, t2b, r2b);
    k_agg2<<<N_NODES / 16, 256, 0, stream>>>(t2b, r2b, rowptr, ssrc, b2, out);
}

// Round 8
// 387.258 us; speedup vs baseline: 2.1244x; 1.1092x over previous
//
#include <hip/hip_runtime.h>
#include <hip/hip_bf16.h>
#include <cstdint>
#include <cstddef>

#define N_NODES 100000
#define N_EDGES 1600000
#define EPSV 1e-5f

// ---- workspace layout (bytes) ----
// rowptr @0 | deg/cursor @400384 | bn @800768 | ssrc @801792
// t1b: N*128 fp8 @7201792 (-> t2b bf16) | r1b: N*128 bf16 @32801792 (-> r2b)
// hpreb: N*128 bf16 @58401792 (bsums overlaps, dead before k_agg1)
// bcur: 98*16 int @84001792 | tmp: E u64 pairs @90000000 (ends ~102.8MB)
#define OFF_ROWPTR 0
#define OFF_DEG    400384
#define OFF_BN     800768
#define OFF_SRC    801792
#define OFF_T1B    7201792
#define OFF_R1B    32801792
#define OFF_HPRE   58401792
#define OFF_BCUR   84001792
#define OFF_TMP    90000000

#define SCAN_NBLK 98      // ceil(100000/1024)
#define GEMM_MBLK 3125    // 100000/32 row-tiles
#define HIST_NBLK 625     // 625*256*10 = 1.6M edges
#define NBUK      98      // bucket = dst>>10
#define PA_EDGES  4096
#define PA_NBLK   391     // ceil(1.6M/4096)

typedef short v8s __attribute__((ext_vector_type(8)));
typedef float v4f __attribute__((ext_vector_type(4)));
typedef float v2f __attribute__((ext_vector_type(2)));

__device__ __forceinline__ float bf2f(unsigned short u) {
    return __uint_as_float(((unsigned int)u) << 16);
}
__device__ __forceinline__ float bf2f_lo(unsigned int u) {
    return __uint_as_float(u << 16);
}
__device__ __forceinline__ float bf2f_hi(unsigned int u) {
    return __uint_as_float(u & 0xffff0000u);
}
__device__ __forceinline__ unsigned short f2bf(float f) {
    unsigned int u = __float_as_uint(f);
    u += 0x7fffu + ((u >> 16) & 1u);   // round-to-nearest-even
    return (unsigned short)(u >> 16);
}
__device__ __forceinline__ unsigned int pk2(float a, float b) {
    return (unsigned int)f2bf(a) | ((unsigned int)f2bf(b) << 16);
}
__device__ __forceinline__ unsigned char f2fp8(float v) {
    return (unsigned char)(__builtin_amdgcn_cvt_pk_fp8_f32(v, v, 0, 0) & 0xff);
}

// ---------- CSR scan ----------
__global__ __launch_bounds__(1024) void k_scan_a(const int* __restrict__ deg, int* __restrict__ rowptr,
                                                 int* __restrict__ bsums) {
    __shared__ int s[1024];
    const int t = threadIdx.x;
    const int i = blockIdx.x * 1024 + t;
    int v = (i < N_NODES) ? deg[i] : 0;
    s[t] = v;
    __syncthreads();
    for (int off = 1; off < 1024; off <<= 1) {
        int u = (t >= off) ? s[t - off] : 0;
        __syncthreads();
        s[t] += u;
        __syncthreads();
    }
    if (i < N_NODES) rowptr[i] = s[t] - v;
    if (t == 1023) bsums[blockIdx.x] = s[1023];
}

__global__ __launch_bounds__(128) void k_scan_b(int* __restrict__ bsums) {
    __shared__ int s[128];
    const int t = threadIdx.x;
    int v = (t < SCAN_NBLK) ? bsums[t] : 0;
    s[t] = v;
    __syncthreads();
    for (int off = 1; off < 128; off <<= 1) {
        int u = (t >= off) ? s[t - off] : 0;
        __syncthreads();
        s[t] += u;
        __syncthreads();
    }
    if (t < SCAN_NBLK) bsums[t] = s[t] - v;
}

// also initializes the bucket write cursors (bcur, padded x16 to avoid line sharing)
__global__ __launch_bounds__(1024) void k_scan_c(int* __restrict__ rowptr, int* __restrict__ cursor,
                                                 const int* __restrict__ bsums, int* __restrict__ bcur) {
    const int i = blockIdx.x * 1024 + threadIdx.x;
    if (i < N_NODES) {
        int r = rowptr[i] + bsums[blockIdx.x];
        rowptr[i] = r;
        cursor[i] = r;
        if ((i & 1023) == 0) bcur[(i >> 10) * 16] = r;
    }
    if (i == N_NODES) rowptr[N_NODES] = N_EDGES;
}

// ---------- pass A: bucket-partition edges into tmp (contiguous burst writes) ----------
__global__ __launch_bounds__(256) void k_partA(const int* __restrict__ esrc, const int* __restrict__ edst,
                                               int* __restrict__ bcur,
                                               unsigned long long* __restrict__ tmp) {
    __shared__ int hist[NBUK];
    __shared__ int loffx[NBUK];
    __shared__ int pos[NBUK];
    __shared__ int gbase[NBUK];
    __shared__ int sc[128];
    __shared__ unsigned long long stage[PA_EDGES];  // 32 KB
    __shared__ unsigned char bkt[PA_EDGES];         // 4 KB
    const int t = threadIdx.x;
    const int e0 = blockIdx.x * PA_EDGES;
    const int cnt = min(PA_EDGES, N_EDGES - e0);

    for (int b = t; b < NBUK; b += 256) hist[b] = 0;
    __syncthreads();

    int esr[16], eds[16];
#pragma unroll
    for (int j = 0; j < 16; ++j) {
        int li = t + j * 256;
        if (li < cnt) {
            esr[j] = esrc[e0 + li];
            eds[j] = edst[e0 + li];
            atomicAdd(&hist[eds[j] >> 10], 1);
        } else {
            eds[j] = -1;
        }
    }
    __syncthreads();

    // scan the 98 bucket counts (Hillis-Steele over first 128 threads)
    if (t < 128) sc[t] = (t < NBUK) ? hist[t] : 0;
    __syncthreads();
    for (int off = 1; off < 128; off <<= 1) {
        int u = (t >= off && t < 128) ? sc[t - off] : 0;
        __syncthreads();
        if (t < 128) sc[t] += u;
        __syncthreads();
    }
    if (t < NBUK) {
        int ex = sc[t] - hist[t];
        loffx[t] = ex;
        pos[t] = ex;
        gbase[t] = atomicAdd(&bcur[t * 16], hist[t]);
    }
    __syncthreads();

    // stage into LDS in bucket order
#pragma unroll
    for (int j = 0; j < 16; ++j) {
        if (eds[j] >= 0) {
            int b = eds[j] >> 10;
            int s = atomicAdd(&pos[b], 1);
            stage[s] = (unsigned long long)(unsigned int)esr[j] |
                       ((unsigned long long)(unsigned int)eds[j] << 32);
            bkt[s] = (unsigned char)b;
        }
    }
    __syncthreads();

    // contiguous burst write-out
    for (int i = t; i < cnt; i += 256) {
        int b = bkt[i];
        tmp[(size_t)gbase[b] + (i - loffx[b])] = stage[i];
    }
}

// ---------- pass B: per-bucket local scatter (L2-resident region) ----------
__global__ __launch_bounds__(1024) void k_partB(const unsigned long long* __restrict__ tmp,
                                                const int* __restrict__ rowptr,
                                                int* __restrict__ cursor, int* __restrict__ ssrc) {
    const int b = blockIdx.x;              // 98 blocks
    const int lo = rowptr[b << 10];
    const int hi = (b == NBUK - 1) ? N_EDGES : rowptr[(b + 1) << 10];
    for (int i = lo + threadIdx.x; i < hi; i += 1024) {
        unsigned long long p = tmp[i];
        int src = (int)(unsigned int)(p & 0xffffffffull);
        int dst = (int)(unsigned int)(p >> 32);
        int q = atomicAdd(&cursor[dst], 1);
        ssrc[q] = src;
    }
}

// ---------- fused: degree histogram (blocks 0..624) + layer-1 MFMA GEMM ----------
__global__ __launch_bounds__(256) void k_gemm1h(const float* __restrict__ x, const float* __restrict__ Wl,
                                                const float* __restrict__ Wr,
                                                unsigned char* __restrict__ t1b8,
                                                unsigned short* __restrict__ r1b,
                                                const int* __restrict__ dst, int* __restrict__ deg) {
    const int t = threadIdx.x;
    if (blockIdx.x < HIST_NBLK) {
        int base = blockIdx.x * 2560 + t;
#pragma unroll
        for (int i = 0; i < 10; ++i) atomicAdd(&deg[dst[base + i * 256]], 1);
        return;
    }
    __shared__ unsigned short As[32 * 128];
    __shared__ unsigned short Bs[128 * 128];
    const int id = blockIdx.x - HIST_NBLK;
    const int half = id / GEMM_MBLK;
    const int blk = id % GEMM_MBLK;
    const size_t n0 = (size_t)blk * 32;
    const float* __restrict__ W = half ? Wr : Wl;

    {
        const int r = t >> 3, s = t & 7;
        const float* xr = x + (n0 + r) * 128 + s * 16;
        float4 f0 = *(const float4*)(xr + 0);
        float4 f1 = *(const float4*)(xr + 4);
        float4 f2 = *(const float4*)(xr + 8);
        float4 f3 = *(const float4*)(xr + 12);
        uint4 p0 = { pk2(f0.x, f0.y), pk2(f0.z, f0.w), pk2(f1.x, f1.y), pk2(f1.z, f1.w) };
        uint4 p1 = { pk2(f2.x, f2.y), pk2(f2.z, f2.w), pk2(f3.x, f3.y), pk2(f3.z, f3.w) };
        int sw = (r & 7) << 3;
        *(uint4*)&As[(r * 128 + s * 16 + 0) ^ sw] = p0;
        *(uint4*)&As[(r * 128 + s * 16 + 8) ^ sw] = p1;
    }
    {
        const int n = t & 127, kh = t >> 7;
        const float* wc = W + n;
        int sw = (n & 7) << 3;
#pragma unroll
        for (int k = kh * 64; k < kh * 64 + 64; k += 8) {
            float a0 = wc[(k + 0) * 128], a1 = wc[(k + 1) * 128];
            float a2 = wc[(k + 2) * 128], a3 = wc[(k + 3) * 128];
            float a4 = wc[(k + 4) * 128], a5 = wc[(k + 5) * 128];
            float a6 = wc[(k + 6) * 128], a7 = wc[(k + 7) * 128];
            uint4 p = { pk2(a0, a1), pk2(a2, a3), pk2(a4, a5), pk2(a6, a7) };
            *(uint4*)&Bs[(n * 128 + k) ^ sw] = p;
        }
    }
    __syncthreads();

    const int w = t >> 6, l = t & 63;
    const int lr = l & 15, lg = l >> 4;
    v4f acc00 = {0.f, 0.f, 0.f, 0.f}, acc01 = acc00, acc10 = acc00, acc11 = acc00;
    const int swA = (lr & 7) << 3;
    const int nA = w * 32 + lr;
    const int swB = (nA & 7) << 3;
#pragma unroll
    for (int ks = 0; ks < 4; ++ks) {
        const int ka = ks * 32 + lg * 8;
        v8s a0 = *(const v8s*)&As[(lr * 128 + ka) ^ swA];
        v8s a1 = *(const v8s*)&As[((16 + lr) * 128 + ka) ^ swA];
        v8s b0 = *(const v8s*)&Bs[(nA * 128 + ka) ^ swB];
        v8s b1 = *(const v8s*)&Bs[((nA + 16) * 128 + ka) ^ swB];
        acc00 = __builtin_amdgcn_mfma_f32_16x16x32_bf16(a0, b0, acc00, 0, 0, 0);
        acc01 = __builtin_amdgcn_mfma_f32_16x16x32_bf16(a0, b1, acc01, 0, 0, 0);
        acc10 = __builtin_amdgcn_mfma_f32_16x16x32_bf16(a1, b0, acc10, 0, 0, 0);
        acc11 = __builtin_amdgcn_mfma_f32_16x16x32_bf16(a1, b1, acc11, 0, 0, 0);
    }
    const int col0 = w * 32 + lr;
    if (half == 0) {
#pragma unroll
        for (int reg = 0; reg < 4; ++reg) {
            size_t row0 = n0 + lg * 4 + reg;
            size_t row1 = row0 + 16;
            t1b8[row0 * 128 + col0]      = f2fp8(acc00[reg]);
            t1b8[row0 * 128 + col0 + 16] = f2fp8(acc01[reg]);
            t1b8[row1 * 128 + col0]      = f2fp8(acc10[reg]);
            t1b8[row1 * 128 + col0 + 16] = f2fp8(acc11[reg]);
        }
    } else {
#pragma unroll
        for (int reg = 0; reg < 4; ++reg) {
            size_t row0 = n0 + lg * 4 + reg;
            size_t row1 = row0 + 16;
            r1b[row0 * 128 + col0]      = f2bf(acc00[reg]);
            r1b[row0 * 128 + col0 + 16] = f2bf(acc01[reg]);
            r1b[row1 * 128 + col0]      = f2bf(acc10[reg]);
            r1b[row1 * 128 + col0 + 16] = f2bf(acc11[reg]);
        }
    }
}

// ---------- layer 1 aggregate: one row per wave, fp8 ushort (2 features) per lane ----------
__global__ __launch_bounds__(256) void k_agg1(const unsigned char* __restrict__ t1b8,
                                              const unsigned short* __restrict__ r1b,
                                              const int* __restrict__ rowptr,
                                              const int* __restrict__ ssrc, const float* __restrict__ b1,
                                              unsigned short* __restrict__ hpreb, float* __restrict__ bn) {
    const int wv = threadIdx.x >> 6;
    const int l  = threadIdx.x & 63;
    const int nbase = blockIdx.x * 32;
    const float bias0 = b1[2 * l], bias1 = b1[2 * l + 1];
    float sa0 = 0.f, sa1 = 0.f, sq0 = 0.f, sq1 = 0.f;

    for (int r = wv; r < 32; r += 4) {
        const int n = nbase + r;
        const int lo = rowptr[n], hi = rowptr[n + 1];
        float a0 = 0.f, a1 = 0.f, b0 = 0.f, b1f = 0.f;
        int i = lo;
        for (; i + 8 <= hi; i += 8) {
            int s0 = ssrc[i], s1 = ssrc[i + 1], s2 = ssrc[i + 2], s3 = ssrc[i + 3];
            int s4 = ssrc[i + 4], s5 = ssrc[i + 5], s6 = ssrc[i + 6], s7 = ssrc[i + 7];
            unsigned short u0 = *(const unsigned short*)&t1b8[(size_t)s0 * 128 + 2 * l];
            unsigned short u1 = *(const unsigned short*)&t1b8[(size_t)s1 * 128 + 2 * l];
            unsigned short u2 = *(const unsigned short*)&t1b8[(size_t)s2 * 128 + 2 * l];
            unsigned short u3 = *(const unsigned short*)&t1b8[(size_t)s3 * 128 + 2 * l];
            unsigned short u4 = *(const unsigned short*)&t1b8[(size_t)s4 * 128 + 2 * l];
            unsigned short u5 = *(const unsigned short*)&t1b8[(size_t)s5 * 128 + 2 * l];
            unsigned short u6 = *(const unsigned short*)&t1b8[(size_t)s6 * 128 + 2 * l];
            unsigned short u7 = *(const unsigned short*)&t1b8[(size_t)s7 * 128 + 2 * l];
            v2f f0 = __builtin_amdgcn_cvt_pk_f32_fp8((int)u0, 0);
            v2f f1 = __builtin_amdgcn_cvt_pk_f32_fp8((int)u1, 0);
            v2f f2 = __builtin_amdgcn_cvt_pk_f32_fp8((int)u2, 0);
            v2f f3 = __builtin_amdgcn_cvt_pk_f32_fp8((int)u3, 0);
            v2f f4 = __builtin_amdgcn_cvt_pk_f32_fp8((int)u4, 0);
            v2f f5 = __builtin_amdgcn_cvt_pk_f32_fp8((int)u5, 0);
            v2f f6 = __builtin_amdgcn_cvt_pk_f32_fp8((int)u6, 0);
            v2f f7 = __builtin_amdgcn_cvt_pk_f32_fp8((int)u7, 0);
            a0 += f0[0] + f1[0]; a1 += f0[1] + f1[1];
            b0 += f2[0] + f3[0]; b1f += f2[1] + f3[1];
            a0 += f4[0] + f5[0]; a1 += f4[1] + f5[1];
            b0 += f6[0] + f7[0]; b1f += f6[1] + f7[1];
        }
        for (; i < hi; ++i) {
            unsigned short u = *(const unsigned short*)&t1b8[(size_t)ssrc[i] * 128 + 2 * l];
            v2f f = __builtin_amdgcn_cvt_pk_f32_fp8((int)u, 0);
            a0 += f[0]; a1 += f[1];
        }
        float c = (float)(hi - lo);
        if (c < 1.f) c = 1.f;
        float inv = 1.0f / c;
        unsigned int ur = *(const unsigned int*)&r1b[(size_t)n * 128 + 2 * l];
        float v0 = (a0 + b0) * inv + bias0 + bf2f_lo(ur);
        float v1 = (a1 + b1f) * inv + bias1 + bf2f_hi(ur);
        *(unsigned int*)&hpreb[(size_t)n * 128 + 2 * l] = pk2(v0, v1);
        sa0 += v0; sa1 += v1; sq0 += v0 * v0; sq1 += v1 * v1;
    }

    __shared__ float red[2][4][128];
    red[0][wv][2 * l] = sa0; red[0][wv][2 * l + 1] = sa1;
    red[1][wv][2 * l] = sq0; red[1][wv][2 * l + 1] = sq1;
    __syncthreads();
    int t = threadIdx.x;
    if (t < 128) {
        atomicAdd(&bn[t], red[0][0][t] + red[0][1][t] + red[0][2][t] + red[0][3][t]);
    } else {
        int f = t - 128;
        atomicAdd(&bn[128 + f], red[1][0][f] + red[1][1][f] + red[1][2][f] + red[1][3][f]);
    }
}

// ---------- BN finalize ----------
__global__ void k_bnfin(float* __restrict__ bn, const float* __restrict__ gamma, const float* __restrict__ beta) {
    int f = threadIdx.x;  // 128
    float mean = bn[f] * (1.0f / N_NODES);
    float var = bn[128 + f] * (1.0f / N_NODES) - mean * mean;
    float sc = gamma[f] * rsqrtf(var + EPSV);
    bn[f] = sc;
    bn[128 + f] = beta[f] - mean * sc;
}

// ---------- layer 2 MFMA GEMM with fused BN+ReLU ----------
__global__ __launch_bounds__(256) void k_gemm2m(const unsigned short* __restrict__ hpreb,
                                                const float* __restrict__ bnp,
                                                const float* __restrict__ Wl, const float* __restrict__ Wr,
                                                unsigned short* __restrict__ t2b,
                                                unsigned short* __restrict__ r2b) {
    __shared__ unsigned short As[32 * 128];
    __shared__ unsigned short Bs[128 * 128];
    const int t = threadIdx.x;
    const size_t n0 = (size_t)blockIdx.x * 32;

    {
        const int r = t >> 3, s = t & 7;
        const unsigned short* hr = hpreb + (n0 + r) * 128 + s * 16;
        uint4 h0 = *(const uint4*)(hr + 0);
        uint4 h1 = *(const uint4*)(hr + 8);
        unsigned int hv[8] = { h0.x, h0.y, h0.z, h0.w, h1.x, h1.y, h1.z, h1.w };
        float v[16];
#pragma unroll
        for (int j = 0; j < 8; ++j) {
            v[2 * j]     = bf2f_lo(hv[j]);
            v[2 * j + 1] = bf2f_hi(hv[j]);
        }
#pragma unroll
        for (int j = 0; j < 16; ++j) {
            int f = s * 16 + j;
            float val = fmaf(bnp[f], v[j], bnp[128 + f]);
            v[j] = val > 0.f ? val : 0.f;
        }
        uint4 p0 = { pk2(v[0], v[1]), pk2(v[2], v[3]), pk2(v[4], v[5]), pk2(v[6], v[7]) };
        uint4 p1 = { pk2(v[8], v[9]), pk2(v[10], v[11]), pk2(v[12], v[13]), pk2(v[14], v[15]) };
        int sw = (r & 7) << 3;
        *(uint4*)&As[(r * 128 + s * 16 + 0) ^ sw] = p0;
        *(uint4*)&As[(r * 128 + s * 16 + 8) ^ sw] = p1;
    }
    {
        const int n = t & 127, kh = t >> 7;
        const float* wc = (n < 64) ? (Wl + n) : (Wr + (n - 64));
        int sw = (n & 7) << 3;
#pragma unroll
        for (int k = kh * 64; k < kh * 64 + 64; k += 8) {
            float a0 = wc[(k + 0) * 64], a1 = wc[(k + 1) * 64];
            float a2 = wc[(k + 2) * 64], a3 = wc[(k + 3) * 64];
            float a4 = wc[(k + 4) * 64], a5 = wc[(k + 5) * 64];
            float a6 = wc[(k + 6) * 64], a7 = wc[(k + 7) * 64];
            uint4 p = { pk2(a0, a1), pk2(a2, a3), pk2(a4, a5), pk2(a6, a7) };
            *(uint4*)&Bs[(n * 128 + k) ^ sw] = p;
        }
    }
    __syncthreads();

    const int w = t >> 6, l = t & 63;
    const int lr = l & 15, lg = l >> 4;
    v4f acc00 = {0.f, 0.f, 0.f, 0.f}, acc01 = acc00, acc10 = acc00, acc11 = acc00;
    const int swA = (lr & 7) << 3;
    const int nA = w * 32 + lr;
    const int swB = (nA & 7) << 3;
#pragma unroll
    for (int ks = 0; ks < 4; ++ks) {
        const int ka = ks * 32 + lg * 8;
        v8s a0 = *(const v8s*)&As[(lr * 128 + ka) ^ swA];
        v8s a1 = *(const v8s*)&As[((16 + lr) * 128 + ka) ^ swA];
        v8s b0 = *(const v8s*)&Bs[(nA * 128 + ka) ^ swB];
        v8s b1 = *(const v8s*)&Bs[((nA + 16) * 128 + ka) ^ swB];
        acc00 = __builtin_amdgcn_mfma_f32_16x16x32_bf16(a0, b0, acc00, 0, 0, 0);
        acc01 = __builtin_amdgcn_mfma_f32_16x16x32_bf16(a0, b1, acc01, 0, 0, 0);
        acc10 = __builtin_amdgcn_mfma_f32_16x16x32_bf16(a1, b0, acc10, 0, 0, 0);
        acc11 = __builtin_amdgcn_mfma_f32_16x16x32_bf16(a1, b1, acc11, 0, 0, 0);
    }
    unsigned short* __restrict__ ob = (w < 2) ? t2b : r2b;
    const int col0 = (w < 2) ? (w * 32 + lr) : ((w - 2) * 32 + lr);
#pragma unroll
    for (int reg = 0; reg < 4; ++reg) {
        size_t row0 = n0 + lg * 4 + reg;
        size_t row1 = row0 + 16;
        ob[row0 * 64 + col0]      = f2bf(acc00[reg]);
        ob[row0 * 64 + col0 + 16] = f2bf(acc01[reg]);
        ob[row1 * 64 + col0]      = f2bf(acc10[reg]);
        ob[row1 * 64 + col0 + 16] = f2bf(acc11[reg]);
    }
}

// ---------- layer 2 aggregate ----------
__global__ __launch_bounds__(256) void k_agg2(const unsigned short* __restrict__ t2b,
                                              const unsigned short* __restrict__ r2b,
                                              const int* __restrict__ rowptr,
                                              const int* __restrict__ ssrc, const float* __restrict__ b2,
                                              float* __restrict__ out) {
    const int wv = threadIdx.x >> 6;
    const int l  = threadIdx.x & 63;
    const int nbase = blockIdx.x * 16;
    const float bias = b2[l];

    for (int r = wv; r < 16; r += 4) {
        const int n = nbase + r;
        const int lo = rowptr[n], hi = rowptr[n + 1];
        float a0 = 0.f, a1 = 0.f;
        int i = lo;
        for (; i + 8 <= hi; i += 8) {
            int s0 = ssrc[i], s1 = ssrc[i + 1], s2 = ssrc[i + 2], s3 = ssrc[i + 3];
            int s4 = ssrc[i + 4], s5 = ssrc[i + 5], s6 = ssrc[i + 6], s7 = ssrc[i + 7];
            float f0 = bf2f(t2b[(size_t)s0 * 64 + l]);
            float f1 = bf2f(t2b[(size_t)s1 * 64 + l]);
            float f2 = bf2f(t2b[(size_t)s2 * 64 + l]);
            float f3 = bf2f(t2b[(size_t)s3 * 64 + l]);
            float f4 = bf2f(t2b[(size_t)s4 * 64 + l]);
            float f5 = bf2f(t2b[(size_t)s5 * 64 + l]);
            float f6 = bf2f(t2b[(size_t)s6 * 64 + l]);
            float f7 = bf2f(t2b[(size_t)s7 * 64 + l]);
            a0 += (f0 + f1) + (f2 + f3);
            a1 += (f4 + f5) + (f6 + f7);
        }
        for (; i < hi; ++i) a0 += bf2f(t2b[(size_t)ssrc[i] * 64 + l]);
        float c = (float)(hi - lo);
        if (c < 1.f) c = 1.f;
        out[(size_t)n * 64 + l] = (a0 + a1) / c + bias + bf2f(r2b[(size_t)n * 64 + l]);
    }
}

extern "C" void kernel_launch(void* const* d_in, const int* in_sizes, int n_in,
                              void* d_out, int out_size, void* d_ws, size_t ws_size,
                              hipStream_t stream) {
    const float* x      = (const float*)d_in[0];
    const int*   ei     = (const int*)d_in[1];
    const float* Wl1    = (const float*)d_in[2];
    const float* b1     = (const float*)d_in[3];
    const float* Wr1    = (const float*)d_in[4];
    const float* gamma1 = (const float*)d_in[5];
    const float* beta1  = (const float*)d_in[6];
    const float* Wl2    = (const float*)d_in[7];
    const float* b2     = (const float*)d_in[8];
    const float* Wr2    = (const float*)d_in[9];
    float* out = (float*)d_out;

    char* ws = (char*)d_ws;
    int*                rowptr = (int*)(ws + OFF_ROWPTR);
    int*                deg    = (int*)(ws + OFF_DEG);
    float*              bn     = (float*)(ws + OFF_BN);
    int*                ssrc   = (int*)(ws + OFF_SRC);
    unsigned char*      t1b8   = (unsigned char*)(ws + OFF_T1B);
    unsigned short*     r1b    = (unsigned short*)(ws + OFF_R1B);
    unsigned short*     hpreb  = (unsigned short*)(ws + OFF_HPRE);
    unsigned short*     t2b    = (unsigned short*)(ws + OFF_T1B);
    unsigned short*     r2b    = r1b;
    int*                bsums  = (int*)(ws + OFF_HPRE);     // dead before k_agg1
    int*                bcur   = (int*)(ws + OFF_BCUR);
    unsigned long long* tmp    = (unsigned long long*)(ws + OFF_TMP);

    const int* esrc = ei;
    const int* edst = ei + N_EDGES;

    hipMemsetAsync(deg, 0, N_NODES * sizeof(int), stream);
    hipMemsetAsync(bn, 0, 256 * sizeof(float), stream);

    k_gemm1h<<<HIST_NBLK + 2 * GEMM_MBLK, 256, 0, stream>>>(x, Wl1, Wr1, t1b8, r1b, edst, deg);
    k_scan_a<<<SCAN_NBLK, 1024, 0, stream>>>(deg, rowptr, bsums);
    k_scan_b<<<1, 128, 0, stream>>>(bsums);
    k_scan_c<<<SCAN_NBLK, 1024, 0, stream>>>(rowptr, deg, bsums, bcur);
    k_partA<<<PA_NBLK, 256, 0, stream>>>(esrc, edst, bcur, tmp);
    k_partB<<<NBUK, 1024, 0, stream>>>(tmp, rowptr, deg, ssrc);

    k_agg1<<<N_NODES / 32, 256, 0, stream>>>(t1b8, r1b, rowptr, ssrc, b1, hpreb, bn);
    k_bnfin<<<1, 128, 0, stream>>>(bn, gamma1, beta1);
    k_gemm2m<<<GEMM_MBLK, 256, 0, stream>>>(hpreb, bn, Wl2, Wr2, t2b, r2b);
    k_agg2<<<N_NODES / 16, 256, 0, stream>>>(t2b, r2b, rowptr, ssrc, b2, out);
}